// Round 10
// baseline (272.370 us; speedup 1.0000x reference)
//
#include <hip/hip_runtime.h>
#include <hip/hip_bf16.h>
#include <math.h>

// ViT block, B=32 S=256 D=768 H=12 HD=64 MLP=3072. fp32 I/O, bf16 MFMA inside.
//
// ws layout (r23 REMAP, total ~97.8 MB; peak live = gemm1 epoch 97.5MB):
//   [0,        25165824)  out1 fp32 [8192][768]  (residual trunk)
//   [25165824, 37748736)  hb bf16 (pre-attn) ; h2 bf16 (post-attn, overlays hb)
//   [37748736, 88080384)  mb bf16 [8192][3072] gelu(fc1)
//   [88080384, 88375296)  Wc  bf16 [12][192][64] packed qkv weights
//   [88375296, 93093888)  W1b bf16 [3072][768]
//   [93093888, 97812480)  W2b bf16 [768][3072]
//   [97812480, 97821696)  bcb fp32 [12][192] packed qkv bias
//
// Journal notes baked in:
//  - r13 WIN: XCD swizzle on GEMM grids. Keep.
//  - r15: both-sides XOR swizzle; KEY: 128B rows -> key=row&7; 64B rows ->
//    key=(row>>1)&3.
//  - r19 LESSON: launch_bounds 2nd arg caps regs; acc spill = catastrophe.
//  - r20: gemm1 256x192 4-phase grid 512 -> 63.5us.
//  - r22 WIN: gemm2 128x192 BK=64 3-buf 1-barrier/tile vmcnt(5) -> best GEMM
//    structure measured (beat 4-phase: 96 sync edges -> 24).
//  - r23 WIN: fused QKV+attn (K/V LDS-resident, single-pass softmax) -> 267.9.
//  - r24 THIS ROUND: port gemm1 onto the r22 structure: 128x192 BK=64 3-buf,
//    grid 64x16=1024 = exactly 4 sched waves at 1 blk/CU, 1 barrier + 1
//    counted vmcnt per K-tile (NTILES=12, vmcnt(5) steady / vmcnt(0) t>=10).
//    GELU epilogue via Cs[128][200] in dead smem (r20 stride-200 trick).
//    Tripwire: gemm1 >= 64us => revert to r20 version.

static constexpr int Bn = 32, Sn = 256, Dn = 768, Hn = 12, HDn = 64, MLPn = 3072;
static constexpr int NT = Bn * Sn; // 8192 tokens

typedef unsigned short ushort_t;
typedef unsigned int u32;
typedef __attribute__((ext_vector_type(8))) short short8; // 8 bf16 MFMA A/B frag
typedef __attribute__((ext_vector_type(4))) float f32x4;  // MFMA C/D frag

__device__ __forceinline__ float bf2f(ushort_t u) { return __uint_as_float(((u32)u) << 16); }
__device__ __forceinline__ ushort_t f2bf(float f) { // round-to-nearest-even
  u32 u = __float_as_uint(f);
  u += 0x7fffu + ((u >> 16) & 1u);
  return (ushort_t)(u >> 16);
}

// async global->LDS 16B per lane; LDS dest = wave-uniform base + lane*16 (m97/m104)
__device__ __forceinline__ void async_cp16(const ushort_t* g, ushort_t* l) {
  __builtin_amdgcn_global_load_lds(
      (const __attribute__((address_space(1))) u32*)g,
      (__attribute__((address_space(3))) u32*)l, 16, 0, 0);
}

// ------- kernel 0: weight prep + LN1 in ONE launch (independent work) ----------
__global__ __launch_bounds__(256) void k_prep(
    const float* __restrict__ Wq, const float* __restrict__ Wk,
    const float* __restrict__ Wv, const float* __restrict__ bq,
    const float* __restrict__ bk, const float* __restrict__ bv,
    const float* __restrict__ W1, const float* __restrict__ W2,
    const float* __restrict__ x, const float* __restrict__ g1,
    const float* __restrict__ be1,
    ushort_t* __restrict__ Wc, float* __restrict__ bc,
    ushort_t* __restrict__ W1b, ushort_t* __restrict__ W2b,
    ushort_t* __restrict__ hb)
{
  __shared__ float red[8];
  const int bx = blockIdx.x;
  const int tid = threadIdx.x;
  if (bx < 576) {
    int i = bx * 256 + tid; // 0 .. 147455
    int h = i / 12288, rem = i - h * 12288;
    int mat = rem / 4096, w = rem - mat * 4096;
    const float* src = (mat == 0) ? Wq : ((mat == 1) ? Wk : Wv);
    Wc[i] = f2bf(src[h * 4096 + w]);
    if (i < Hn * 192) {
      int h2 = i / 192, r2 = i - h2 * 192;
      int m2 = r2 / 64, e2 = r2 - m2 * 64;
      const float* bs = (m2 == 0) ? bq : ((m2 == 1) ? bk : bv);
      bc[i] = bs[h2 * 64 + e2];
    }
  } else if (bx < 5184) {
    int j = bx - 576;
    const float* src = (j < 2304) ? W1 : W2;
    ushort_t* dst = (j < 2304) ? W1b : W2b;
    int i = (j % 2304) * 256 + tid; // float4 index < 589824
    float4 v = ((const float4*)src)[i];
    ushort4 o;
    o.x = f2bf(v.x); o.y = f2bf(v.y); o.z = f2bf(v.z); o.w = f2bf(v.w);
    ((ushort4*)dst)[i] = o;
  } else {
    const int t = bx - 5184;
    float xv[3];
#pragma unroll
    for (int i = 0; i < 3; i++) xv[i] = x[(size_t)t * Dn + tid + i * 256];
    float s = xv[0] + xv[1] + xv[2];
#pragma unroll
    for (int off = 32; off > 0; off >>= 1) s += __shfl_down(s, off, 64);
    if ((tid & 63) == 0) red[tid >> 6] = s;
    __syncthreads();
    float mean = (red[0] + red[1] + red[2] + red[3]) * (1.0f / 768.0f);
    float d0 = xv[0] - mean, d1 = xv[1] - mean, d2 = xv[2] - mean;
    float s2 = d0 * d0 + d1 * d1 + d2 * d2;
#pragma unroll
    for (int off = 32; off > 0; off >>= 1) s2 += __shfl_down(s2, off, 64);
    if ((tid & 63) == 0) red[4 + (tid >> 6)] = s2;
    __syncthreads();
    float rstd = rsqrtf((red[4] + red[5] + red[6] + red[7]) * (1.0f / 768.0f) + 1e-5f);
#pragma unroll
    for (int i = 0; i < 3; i++) {
      int d = tid + i * 256;
      hb[(size_t)t * Dn + d] = f2bf((xv[i] - mean) * rstd * g1[d] + be1[d]);
    }
  }
}

// ---- kernel 1: FUSED per-(b,h) QKV projection + flash attention ---------------
// r23 EXACT (verified). 384 blocks x 256 thr. LDS 152KB.
__global__ __launch_bounds__(256) void k_fused(
    const ushort_t* __restrict__ hb,  // [NT][768] bf16
    const ushort_t* __restrict__ Wc,  // [12][192][64] bf16
    const float* __restrict__ bc,     // [12][192] fp32
    const float* __restrict__ x,
    float* __restrict__ out1)
{
  __shared__ __align__(16) ushort_t smem[77824];   // 152KB
  ushort_t* Qs  = smem;
  ushort_t* Ks  = smem + 16384;
  ushort_t* Vts = smem + 32768;
  ushort_t* As  = smem + 49152;
  ushort_t* Ws  = smem + 65536;
  ushort_t* Pw  = smem + 49152;      // overlays As/Ws (dead after phase 1)

  const int bh = blockIdx.x;
  const int b_ = bh / Hn, h_ = bh - b_ * Hn;
  const int tid = threadIdx.x;
  const int wave = tid >> 6, lane = tid & 63;
  const int lrow = lane & 15, quad = lane >> 4;
  const int key = lrow & 7;          // 128B-row swizzle key (r15 derivation)
  const int t0 = b_ * Sn;

  { // stage As (256x64, 8 DMA/thr) + Ws (192x64, 6 DMA/thr), swizzled source
    const ushort_t* ga = hb + (size_t)t0 * Dn + h_ * 64;
#pragma unroll
    for (int j = 0; j < 8; ++j) {
      int q = j * 256 + tid;               // chunk 0..2047
      int row = q >> 3;
      int sc = (q & 7) ^ (row & 7);
      async_cp16(ga + (size_t)row * Dn + sc * 8, As + q * 8);
    }
    const ushort_t* gw = Wc + h_ * 12288;
#pragma unroll
    for (int j = 0; j < 6; ++j) {
      int q = j * 256 + tid;               // chunk 0..1535
      int row = q >> 3;
      int sc = (q & 7) ^ (row & 7);
      async_cp16(gw + row * 64 + sc * 8, Ws + q * 8);
    }
  }
  asm volatile("s_waitcnt vmcnt(0)" ::: "memory");
  __syncthreads();

  // ---- phase 1: QKV projection (old k_qkv wave layout, 2 row-halves) ----
  const int wm = (wave >> 1) * 64, wn = (wave & 1) * 96;
  for (int half = 0; half < 2; ++half) {
    f32x4 acc[4][6];
#pragma unroll
    for (int mi = 0; mi < 4; mi++)
#pragma unroll
      for (int ni = 0; ni < 6; ni++) acc[mi][ni] = (f32x4){0.f, 0.f, 0.f, 0.f};

#pragma unroll
    for (int kk = 0; kk < 2; kk++) {
      short8 af[4], wf[6];
#pragma unroll
      for (int mi = 0; mi < 4; mi++)
        af[mi] = *(const short8*)(As + (half * 128 + wm + mi * 16 + lrow) * 64 + ((((kk << 2) + quad)) ^ key) * 8);
#pragma unroll
      for (int ni = 0; ni < 6; ni++)
        wf[ni] = *(const short8*)(Ws + (wn + ni * 16 + lrow) * 64 + ((((kk << 2) + quad)) ^ key) * 8);
#pragma unroll
      for (int mi = 0; mi < 4; mi++)
#pragma unroll
        for (int ni = 0; ni < 6; ni++)
          acc[mi][ni] = __builtin_amdgcn_mfma_f32_16x16x32_bf16(af[mi], wf[ni], acc[mi][ni], 0, 0, 0);
    }

    // epilogue: Q,K -> swizzled LDS; V -> transposed swizzled LDS
#pragma unroll
    for (int ni = 0; ni < 6; ni++) {
      int c = wn + ni * 16 + lrow;       // 0..191
      int mat = c >> 6, e = c & 63;
      float bb = bc[h_ * 192 + c];
      if (mat < 2) {
        ushort_t* dst = (mat == 0) ? Qs : Ks;
#pragma unroll
        for (int mi = 0; mi < 4; mi++) {
#pragma unroll
          for (int r = 0; r < 4; r++) {
            int srow = half * 128 + wm + mi * 16 + quad * 4 + r;
            dst[srow * 64 + (((e >> 3) ^ (srow & 7)) << 3) + (e & 7)] = f2bf(acc[mi][ni][r] + bb);
          }
        }
      } else {
#pragma unroll
        for (int mi = 0; mi < 4; mi++) {
          int c4 = half * 128 + wm + mi * 16 + quad * 4;   // s-col, %8 in {0,4}
          ushort4 pk;
          pk.x = f2bf(acc[mi][ni][0] + bb);
          pk.y = f2bf(acc[mi][ni][1] + bb);
          pk.z = f2bf(acc[mi][ni][2] + bb);
          pk.w = f2bf(acc[mi][ni][3] + bb);
          int cq = c4 >> 3;
          *(ushort4*)(Vts + e * 256 + ((cq ^ (e & 7)) << 3) + (c4 & 7)) = pk;
        }
      }
    }
  }
  __syncthreads();

  // ---- phase 2: per-wave flash attention, K/V resident, single-pass softmax
  ushort_t* Pme = Pw + wave * 4224;    // [16 rows][264] per wave
  for (int p = 0; p < 4; ++p) {
    const int s0 = wave * 64 + p * 16;
    short8 qf[2];
#pragma unroll
    for (int kk = 0; kk < 2; kk++)
      qf[kk] = *(const short8*)(Qs + (s0 + lrow) * 64 + ((((kk << 2) + quad)) ^ key) * 8);

    f32x4 sc[16];
#pragma unroll
    for (int ni = 0; ni < 16; ni++) sc[ni] = (f32x4){0.f, 0.f, 0.f, 0.f};
#pragma unroll
    for (int kk = 0; kk < 2; kk++) {
#pragma unroll
      for (int ni = 0; ni < 16; ni++) {
        short8 kf = *(const short8*)(Ks + (ni * 16 + lrow) * 64 + ((((kk << 2) + quad)) ^ key) * 8);
        sc[ni] = __builtin_amdgcn_mfma_f32_16x16x32_bf16(qf[kk], kf, sc[ni], 0, 0, 0);
      }
    }

    // single-pass softmax over all 256 keys (rows quad*4+r, k-col ni*16+lrow)
    float inv[4];
#pragma unroll
    for (int r = 0; r < 4; r++) {
      float m_ = sc[0][r];
#pragma unroll
      for (int ni = 1; ni < 16; ni++) m_ = fmaxf(m_, sc[ni][r]);
#pragma unroll
      for (int msk = 8; msk >= 1; msk >>= 1) m_ = fmaxf(m_, __shfl_xor(m_, msk, 64));
      float s_ = 0.f;
#pragma unroll
      for (int ni = 0; ni < 16; ni++) {
        float pv = __expf((sc[ni][r] - m_) * 0.125f);
        s_ += pv;
        Pme[(quad * 4 + r) * 264 + ni * 16 + lrow] = f2bf(pv);
      }
#pragma unroll
      for (int msk = 8; msk >= 1; msk >>= 1) s_ += __shfl_xor(s_, msk, 64);
      inv[r] = 1.0f / s_;
    }
    asm volatile("s_waitcnt lgkmcnt(0)" ::: "memory");
    __builtin_amdgcn_sched_barrier(0);

    // PV: of[et] (16 q-rows x 64 e-cols), K=256 in 8 slices
    f32x4 of[4];
#pragma unroll
    for (int et = 0; et < 4; et++) of[et] = (f32x4){0.f, 0.f, 0.f, 0.f};
#pragma unroll
    for (int ks = 0; ks < 8; ks++) {
      short8 pf = *(const short8*)(Pme + lrow * 264 + ks * 32 + quad * 8);
#pragma unroll
      for (int et = 0; et < 4; et++) {
        short8 vf = *(const short8*)(Vts + (et * 16 + lrow) * 256 + ((((ks << 2) + quad)) ^ key) * 8);
        of[et] = __builtin_amdgcn_mfma_f32_16x16x32_bf16(pf, vf, of[et], 0, 0, 0);
      }
    }

    const size_t obase = ((size_t)t0 + s0) * Dn + h_ * 64;
#pragma unroll
    for (int r = 0; r < 4; r++) {
      float rl = inv[r];
      int row = quad * 4 + r;
#pragma unroll
      for (int et = 0; et < 4; et++) {
        size_t idx = obase + (size_t)row * Dn + et * 16 + lrow;
        out1[idx] = of[et][r] * rl + x[idx];
      }
    }
  }
}

// ---------------- kernel 4: LN2 (one WG per token) -----------------------------
__global__ __launch_bounds__(256) void k_ln2(
    const float* __restrict__ in, const float* __restrict__ g2,
    const float* __restrict__ be2, ushort_t* __restrict__ h2)
{
  const int t = blockIdx.x, tid = threadIdx.x;
  __shared__ float red[8];
  float xv[3];
#pragma unroll
  for (int i = 0; i < 3; i++) xv[i] = in[(size_t)t * Dn + tid + i * 256];
  float s = xv[0] + xv[1] + xv[2];
#pragma unroll
  for (int off = 32; off > 0; off >>= 1) s += __shfl_down(s, off, 64);
  if ((tid & 63) == 0) red[tid >> 6] = s;
  __syncthreads();
  float mean = (red[0] + red[1] + red[2] + red[3]) * (1.0f / 768.0f);
  float d0 = xv[0] - mean, d1 = xv[1] - mean, d2 = xv[2] - mean;
  float s2 = d0 * d0 + d1 * d1 + d2 * d2;
#pragma unroll
  for (int off = 32; off > 0; off >>= 1) s2 += __shfl_down(s2, off, 64);
  if ((tid & 63) == 0) red[4 + (tid >> 6)] = s2;
  __syncthreads();
  float rstd = rsqrtf((red[4] + red[5] + red[6] + red[7]) * (1.0f / 768.0f) + 1e-5f);
#pragma unroll
  for (int i = 0; i < 3; i++) {
    int d = tid + i * 256;
    h2[(size_t)t * Dn + d] = f2bf((xv[i] - mean) * rstd * g2[d] + be2[d]);
  }
}

// ---- kernel 5: fc1 MFMA GEMM, 128x192 tile, BK=64, 3-buf 1-barrier/tile -------
// r24: r22's proven structure (best GEMM schedule measured) with KD=768.
// 512 thr / 8 waves (2Mx4N), per-wave 64x48 (acc[4][3]=48). LDS 120KB =
// 3 bufs x (A 128x64 + B 192x64) -> 1 blk/CU; grid 64x16=1024 = exactly 4
// sched waves. Per tile: {14 ds_read || stage(t+2) -> lgkm0 -> prio -> 24 MFMA
// (x2 kk) -> vmcnt(5) -> bar}. NTILES=12: vmcnt(5) steady, vmcnt(0) t>=10.
// key=row&7. Epilogue: GELU+bias -> Cs[128][200] in dead smem -> 16B stores.
__global__ __launch_bounds__(512, 2) void k_gemm1(
    const ushort_t* __restrict__ A,   // h2 [8192][768] bf16
    const ushort_t* __restrict__ Bw,  // W1b [3072][768] bf16
    const float* __restrict__ bias,   // bm1 [3072]
    ushort_t* __restrict__ CoutB)     // mb [8192][3072] bf16
{
  constexpr int KD = Dn;              // 768
  constexpr int NTILES = 12;          // 768/64
  constexpr int BUFU = 20480;         // ushorts/buffer: A 8192 + B 12288
  __shared__ __align__(16) ushort_t smem[61440];   // 120KB (3 buffers)
  const int b = blockIdx.x;
  const int xcd = b & 7, slot = b >> 3;   // 128 slots per XCD (1024 = 8*128)
  const int cc = slot % 16, rloc = slot / 16;      // 16 col-tiles, 8 row-bands
  const int m0 = (xcd * 8 + rloc) * 128, n0 = cc * 192;
  const int tid = threadIdx.x;
  const int wave = tid >> 6, lane = tid & 63;
  const int wm2 = (wave >> 2) * 64, wn2 = (wave & 3) * 48;
  const int lrow = lane & 15, quad = lane >> 4;
  const int key = lrow & 7;           // 128B rows: key=row&7

  f32x4 acc[4][3];
#pragma unroll
  for (int mi = 0; mi < 4; mi++)
#pragma unroll
    for (int ni = 0; ni < 3; ni++) acc[mi][ni] = (f32x4){0.f, 0.f, 0.f, 0.f};

  // stage full K-tile (A 128x64 + B 192x64): 5 DMA/thread
  auto stageT = [&](int t) {
    if (t >= NTILES) return;
    const int k0 = t * 64;
    ushort_t* bufA = smem + (t % 3) * BUFU;
    ushort_t* bufB = bufA + 8192;
#pragma unroll
    for (int j = 0; j < 2; ++j) {        // A: 128 rows x 8 chunks = 1024
      int q = j * 512 + tid;
      int row = q >> 3;
      int sc = (q & 7) ^ (row & 7);
      async_cp16(A + (size_t)(m0 + row) * KD + k0 + sc * 8, bufA + q * 8);
    }
#pragma unroll
    for (int j = 0; j < 3; ++j) {        // B: 192 rows x 8 chunks = 1536
      int q = j * 512 + tid;
      int row = q >> 3;
      int sc = (q & 7) ^ (row & 7);
      async_cp16(Bw + (size_t)(n0 + row) * KD + k0 + sc * 8, bufB + q * 8);
    }
  };

  // prologue: stage tiles 0,1; wait tile0 (5 newest = tile1's stay in flight)
  stageT(0); stageT(1);
  asm volatile("s_waitcnt vmcnt(5)" ::: "memory");
  __builtin_amdgcn_s_barrier();
  __builtin_amdgcn_sched_barrier(0);

  short8 af[4], bf[3];
  for (int t = 0; t < NTILES; ++t) {
    const ushort_t* Ab = smem + (t % 3) * BUFU;
    const ushort_t* Bb = Ab + 8192;

#pragma unroll
    for (int mi = 0; mi < 4; ++mi)
      af[mi] = *(const short8*)(Ab + (wm2 + mi * 16 + lrow) * 64 + ((quad ^ key) * 8));
#pragma unroll
    for (int ni = 0; ni < 3; ++ni)
      bf[ni] = *(const short8*)(Bb + (wn2 + ni * 16 + lrow) * 64 + ((quad ^ key) * 8));
    stageT(t + 2);
    asm volatile("s_waitcnt lgkmcnt(0)" ::: "memory");
    __builtin_amdgcn_sched_barrier(0);
    __builtin_amdgcn_s_setprio(1);
#pragma unroll
    for (int mi = 0; mi < 4; ++mi)
#pragma unroll
      for (int ni = 0; ni < 3; ++ni)
        acc[mi][ni] = __builtin_amdgcn_mfma_f32_16x16x32_bf16(af[mi], bf[ni], acc[mi][ni], 0, 0, 0);
    __builtin_amdgcn_s_setprio(0);
#pragma unroll
    for (int mi = 0; mi < 4; ++mi)
      af[mi] = *(const short8*)(Ab + (wm2 + mi * 16 + lrow) * 64 + (((4 + quad) ^ key) * 8));
#pragma unroll
    for (int ni = 0; ni < 3; ++ni)
      bf[ni] = *(const short8*)(Bb + (wn2 + ni * 16 + lrow) * 64 + (((4 + quad) ^ key) * 8));
    asm volatile("s_waitcnt lgkmcnt(0)" ::: "memory");
    __builtin_amdgcn_sched_barrier(0);
    __builtin_amdgcn_s_setprio(1);
#pragma unroll
    for (int mi = 0; mi < 4; ++mi)
#pragma unroll
      for (int ni = 0; ni < 3; ++ni)
        acc[mi][ni] = __builtin_amdgcn_mfma_f32_16x16x32_bf16(af[mi], bf[ni], acc[mi][ni], 0, 0, 0);
    __builtin_amdgcn_s_setprio(0);
    // ledger: retire t+1's 5 DMAs (issued 1 full tile ago); keep t+2's in flight
    if (t < NTILES - 2) {
      asm volatile("s_waitcnt vmcnt(5)" ::: "memory");
    } else {
      asm volatile("s_waitcnt vmcnt(0)" ::: "memory");
    }
    __builtin_amdgcn_s_barrier();
    __builtin_amdgcn_sched_barrier(0);
  }

  // ---- epilogue: GELU+bias -> Cs[128][200] (dead smem) -> coalesced 16B stores
  float bwv[3];
#pragma unroll
  for (int ni = 0; ni < 3; ++ni) bwv[ni] = bias[n0 + wn2 + ni * 16 + lrow];
#pragma unroll
  for (int mi = 0; mi < 4; ++mi) {
#pragma unroll
    for (int ni = 0; ni < 3; ++ni) {
      int col = wn2 + ni * 16 + lrow;
#pragma unroll
      for (int r = 0; r < 4; ++r) {
        int row = wm2 + mi * 16 + quad * 4 + r;       // 0..127
        float vv = acc[mi][ni][r] + bwv[ni];
        float u = vv * (0.7978845608f + 0.0356774081f * vv * vv);
        float o = vv / (1.0f + __expf(-2.0f * u));
        smem[row * 200 + col] = f2bf(o);
      }
    }
  }
  __syncthreads();
#pragma unroll
  for (int i = 0; i < 6; ++i) {
    int idx = i * 512 + tid;            // 0..3071 = 128 rows x 24 chunks
    int rr = idx / 24, ck = idx - rr * 24;
    const uint4 v = *(const uint4*)(smem + rr * 200 + ck * 8);
    *(uint4*)(CoutB + (size_t)(m0 + rr) * MLPn + n0 + ck * 8) = v;
  }
}

// ---- kernel 6: fc2 MFMA GEMM, 128x192 tile, BK=64, 3-buf 1-barrier/tile -------
// r22 EXACT (win verified).
__global__ __launch_bounds__(512, 2) void k_gemm2(
    const ushort_t* __restrict__ A,   // mb [8192][3072] bf16
    const ushort_t* __restrict__ Bw,  // W2b [768][3072] bf16
    const float* __restrict__ bias,   // bm2 [768]
    const float* __restrict__ res,    // out1 [8192][768] fp32
    float* __restrict__ out)          // d_out [8192][768] fp32
{
  constexpr int KD = MLPn;            // 3072
  constexpr int N = Dn;               // 768
  constexpr int NTILES = 48;          // 3072/64
  constexpr int BUFU = 20480;         // ushorts/buffer: A 8192 + B 12288
  __shared__ __align__(16) ushort_t smem[61440];   // 120KB (3 buffers)
  const int b = blockIdx.x;
  const int xcd = b & 7, slot = b >> 3;   // 32 slots per XCD (256 = 8*32)
  const int cc = slot & 3, rloc = slot >> 2;       // 4 col-tiles, 8 row-bands
  const int m0 = (xcd * 8 + rloc) * 128, n0 = cc * 192;
  const int tid = threadIdx.x;
  const int wave = tid >> 6, lane = tid & 63;
  const int wm2 = (wave >> 2) * 64, wn2 = (wave & 3) * 48;
  const int lrow = lane & 15, quad = lane >> 4;
  const int key = lrow & 7;           // 128B rows: key=row&7

  f32x4 acc[4][3];
#pragma unroll
  for (int mi = 0; mi < 4; mi++)
#pragma unroll
    for (int ni = 0; ni < 3; ni++) acc[mi][ni] = (f32x4){0.f, 0.f, 0.f, 0.f};

  auto stageT = [&](int t) {
    if (t >= NTILES) return;
    const int k0 = t * 64;
    ushort_t* bufA = smem + (t % 3) * BUFU;
    ushort_t* bufB = bufA + 8192;
#pragma unroll
    for (int j = 0; j < 2; ++j) {        // A: 128 rows x 8 chunks = 1024
      int q = j * 512 + tid;
      int row = q >> 3;
      int sc = (q & 7) ^ (row & 7);
      async_cp16(A + (size_t)(m0 + row) * KD + k0 + sc * 8, bufA + q * 8);
    }
#pragma unroll
    for (int j = 0; j < 3; ++j) {        // B: 192 rows x 8 chunks = 1536
      int q = j * 512 + tid;
      int row = q >> 3;
      int sc = (q & 7) ^ (row & 7);
      async_cp16(Bw + (size_t)(n0 + row) * KD + k0 + sc * 8, bufB + q * 8);
    }
  };

  stageT(0); stageT(1);
  asm volatile("s_waitcnt vmcnt(5)" ::: "memory");
  __builtin_amdgcn_s_barrier();
  __builtin_amdgcn_sched_barrier(0);

  short8 af[4], bf[3];
  for (int t = 0; t < NTILES; ++t) {
    const ushort_t* Ab = smem + (t % 3) * BUFU;
    const ushort_t* Bb = Ab + 8192;

#pragma unroll
    for (int mi = 0; mi < 4; ++mi)
      af[mi] = *(const short8*)(Ab + (wm2 + mi * 16 + lrow) * 64 + ((quad ^ key) * 8));
#pragma unroll
    for (int ni = 0; ni < 3; ++ni)
      bf[ni] = *(const short8*)(Bb + (wn2 + ni * 16 + lrow) * 64 + ((quad ^ key) * 8));
    stageT(t + 2);
    asm volatile("s_waitcnt lgkmcnt(0)" ::: "memory");
    __builtin_amdgcn_sched_barrier(0);
    __builtin_amdgcn_s_setprio(1);
#pragma unroll
    for (int mi = 0; mi < 4; ++mi)
#pragma unroll
      for (int ni = 0; ni < 3; ++ni)
        acc[mi][ni] = __builtin_amdgcn_mfma_f32_16x16x32_bf16(af[mi], bf[ni], acc[mi][ni], 0, 0, 0);
    __builtin_amdgcn_s_setprio(0);
#pragma unroll
    for (int mi = 0; mi < 4; ++mi)
      af[mi] = *(const short8*)(Ab + (wm2 + mi * 16 + lrow) * 64 + (((4 + quad) ^ key) * 8));
#pragma unroll
    for (int ni = 0; ni < 3; ++ni)
      bf[ni] = *(const short8*)(Bb + (wn2 + ni * 16 + lrow) * 64 + (((4 + quad) ^ key) * 8));
    asm volatile("s_waitcnt lgkmcnt(0)" ::: "memory");
    __builtin_amdgcn_sched_barrier(0);
    __builtin_amdgcn_s_setprio(1);
#pragma unroll
    for (int mi = 0; mi < 4; ++mi)
#pragma unroll
      for (int ni = 0; ni < 3; ++ni)
        acc[mi][ni] = __builtin_amdgcn_mfma_f32_16x16x32_bf16(af[mi], bf[ni], acc[mi][ni], 0, 0, 0);
    __builtin_amdgcn_s_setprio(0);
    if (t < NTILES - 2) {
      asm volatile("s_waitcnt vmcnt(5)" ::: "memory");
    } else {
      asm volatile("s_waitcnt vmcnt(0)" ::: "memory");
    }
    __builtin_amdgcn_s_barrier();
    __builtin_amdgcn_sched_barrier(0);
  }

  // fused epilogue: + bias + residual -> fp32 (16-lane x 4B = 64B segments)
#pragma unroll
  for (int ni = 0; ni < 3; ++ni) {
    int col = n0 + wn2 + ni * 16 + lrow;
    float bc = bias[col];
#pragma unroll
    for (int mi = 0; mi < 4; ++mi) {
#pragma unroll
      for (int r = 0; r < 4; ++r) {
        int row = m0 + wm2 + mi * 16 + quad * 4 + r;
        size_t idx = (size_t)row * N + col;
        out[idx] = acc[mi][ni][r] + bc + res[idx];
      }
    }
  }
}

// ---------------- launch --------------------------------------------------------
extern "C" void kernel_launch(void* const* d_in, const int* in_sizes, int n_in,
                              void* d_out, int out_size, void* d_ws, size_t ws_size,
                              hipStream_t stream) {
  (void)in_sizes; (void)n_in; (void)out_size; (void)ws_size;
  const float* x   = (const float*)d_in[0];
  const float* g1  = (const float*)d_in[1];
  const float* be1 = (const float*)d_in[2];
  const float* Wq  = (const float*)d_in[3];
  const float* bq  = (const float*)d_in[4];
  const float* Wk  = (const float*)d_in[5];
  const float* bk  = (const float*)d_in[6];
  const float* Wv  = (const float*)d_in[7];
  const float* bv  = (const float*)d_in[8];
  const float* g2  = (const float*)d_in[9];
  const float* be2 = (const float*)d_in[10];
  const float* W1  = (const float*)d_in[11];
  const float* bm1 = (const float*)d_in[12];
  const float* W2  = (const float*)d_in[13];
  const float* bm2 = (const float*)d_in[14];
  float* outp = (float*)d_out;

  char* ws = (char*)d_ws;
  float*    out1 = (float*)ws;                   // [0, 25165824)
  ushort_t* hb   = (ushort_t*)(ws + 25165824);   // pre-attn bf16
  ushort_t* h2   = (ushort_t*)(ws + 25165824);   // post-attn bf16 (overlays hb)
  ushort_t* mb   = (ushort_t*)(ws + 37748736);
  ushort_t* Wc   = (ushort_t*)(ws + 88080384);
  ushort_t* W1b  = (ushort_t*)(ws + 88375296);
  ushort_t* W2b  = (ushort_t*)(ws + 93093888);
  float*    bcb  = (float*)(ws + 97812480);

  k_prep<<<dim3(5184 + NT), dim3(256), 0, stream>>>(Wq, Wk, Wv, bq, bk, bv, W1, W2,
                                                    x, g1, be1, Wc, bcb, W1b, W2b, hb);
  k_fused<<<dim3(Bn * Hn), dim3(256), 0, stream>>>(hb, Wc, bcb, x, out1);
  k_ln2<<<dim3(NT), dim3(256), 0, stream>>>(out1, g2, be2, h2);
  k_gemm1<<<dim3(1024), dim3(512), 0, stream>>>(h2, W1b, bm1, mb);
  k_gemm2<<<dim3(256), dim3(512), 0, stream>>>(mb, W2b, bm2, out1, outp);
}

// Round 11
// 261.978 us; speedup vs baseline: 1.0397x; 1.0397x over previous
//
#include <hip/hip_runtime.h>
#include <hip/hip_bf16.h>
#include <math.h>

// ViT block, B=32 S=256 D=768 H=12 HD=64 MLP=3072. fp32 I/O, bf16 MFMA inside.
//
// ws layout (r23 REMAP, total ~97.8 MB; peak live = gemm1 epoch 97.5MB):
//   [0,        25165824)  out1 fp32 [8192][768]  (residual trunk)
//   [25165824, 37748736)  hb bf16 (pre-attn) ; h2 bf16 (post-attn, overlays hb)
//   [37748736, 88080384)  mb bf16 [8192][3072] gelu(fc1)
//   [88080384, 88375296)  Wc  bf16 [12][192][64] packed qkv weights
//   [88375296, 93093888)  W1b bf16 [3072][768]
//   [93093888, 97812480)  W2b bf16 [768][3072]
//   [97812480, 97821696)  bcb fp32 [12][192] packed qkv bias
//
// Journal notes baked in:
//  - r13 WIN: XCD swizzle on GEMM grids. Keep.
//  - r15: both-sides XOR swizzle; KEY: 128B rows -> key=row&7; 64B rows ->
//    key=(row>>1)&3.
//  - r19 LESSON: launch_bounds 2nd arg caps regs; acc spill = catastrophe.
//  - r20 WIN: gemm1 256x192 BK=64 4-phase grid 512 -> 63.5us / 43MB. KEPT.
//  - r22 WIN: gemm2 128x192 BK=64 3-buf 1-barrier/tile vmcnt(5).
//  - r23 WIN: fused QKV+attn (K/V LDS-resident, single-pass softmax) -> 267.9.
//  - r24 NEUTRAL: r22-structure port of gemm1 = same 63.5us but FETCH 43->80MB
//    (128-row tile doubles B-refetch; 12-tile K-loop didn't need barrier
//    amortization). REVERTED to r20. gemm1 is schedule-saturated.
//  - r25 THIS ROUND: LN glue. Both LN kernels were one-token-per-block with
//    scalar 4B loads + 2 __syncthreads. Now wave-per-token: 64 lanes x 3
//    float4 (16B/lane sweet spot), butterfly __shfl_xor reduce, ZERO barriers,
//    4 tokens/block. ln2 grid 8192->2048; k_prep LN1 branch same (grid 7232).

static constexpr int Bn = 32, Sn = 256, Dn = 768, Hn = 12, HDn = 64, MLPn = 3072;
static constexpr int NT = Bn * Sn; // 8192 tokens

typedef unsigned short ushort_t;
typedef unsigned int u32;
typedef __attribute__((ext_vector_type(8))) short short8; // 8 bf16 MFMA A/B frag
typedef __attribute__((ext_vector_type(4))) float f32x4;  // MFMA C/D frag

__device__ __forceinline__ float bf2f(ushort_t u) { return __uint_as_float(((u32)u) << 16); }
__device__ __forceinline__ ushort_t f2bf(float f) { // round-to-nearest-even
  u32 u = __float_as_uint(f);
  u += 0x7fffu + ((u >> 16) & 1u);
  return (ushort_t)(u >> 16);
}

// async global->LDS 16B per lane; LDS dest = wave-uniform base + lane*16 (m97/m104)
__device__ __forceinline__ void async_cp16(const ushort_t* g, ushort_t* l) {
  __builtin_amdgcn_global_load_lds(
      (const __attribute__((address_space(1))) u32*)g,
      (__attribute__((address_space(3))) u32*)l, 16, 0, 0);
}

// ------- kernel 0: weight prep + LN1 in ONE launch (independent work) ----------
// blocks [0,576)      : pack Wq|Wk|Wv -> Wc bf16 + bias -> bcb
// blocks [576,5184)   : W1/W2 -> bf16
// blocks [5184,7232)  : LN1, wave-per-token (4 tokens/block, no barriers)
__global__ __launch_bounds__(256) void k_prep(
    const float* __restrict__ Wq, const float* __restrict__ Wk,
    const float* __restrict__ Wv, const float* __restrict__ bq,
    const float* __restrict__ bk, const float* __restrict__ bv,
    const float* __restrict__ W1, const float* __restrict__ W2,
    const float* __restrict__ x, const float* __restrict__ g1,
    const float* __restrict__ be1,
    ushort_t* __restrict__ Wc, float* __restrict__ bc,
    ushort_t* __restrict__ W1b, ushort_t* __restrict__ W2b,
    ushort_t* __restrict__ hb)
{
  const int bx = blockIdx.x;
  const int tid = threadIdx.x;
  if (bx < 576) {
    int i = bx * 256 + tid; // 0 .. 147455
    int h = i / 12288, rem = i - h * 12288;
    int mat = rem / 4096, w = rem - mat * 4096;
    const float* src = (mat == 0) ? Wq : ((mat == 1) ? Wk : Wv);
    Wc[i] = f2bf(src[h * 4096 + w]);
    if (i < Hn * 192) {
      int h2 = i / 192, r2 = i - h2 * 192;
      int m2 = r2 / 64, e2 = r2 - m2 * 64;
      const float* bs = (m2 == 0) ? bq : ((m2 == 1) ? bk : bv);
      bc[i] = bs[h2 * 64 + e2];
    }
  } else if (bx < 5184) {
    int j = bx - 576;
    const float* src = (j < 2304) ? W1 : W2;
    ushort_t* dst = (j < 2304) ? W1b : W2b;
    int i = (j % 2304) * 256 + tid; // float4 index < 589824
    float4 v = ((const float4*)src)[i];
    ushort4 o;
    o.x = f2bf(v.x); o.y = f2bf(v.y); o.z = f2bf(v.z); o.w = f2bf(v.w);
    ((ushort4*)dst)[i] = o;
  } else {
    // LN1: wave-per-token. 64 lanes x 3 float4 = 768 floats; no barriers.
    const int wave = tid >> 6, lane = tid & 63;
    const int t = (bx - 5184) * 4 + wave;
    const float* row = x + (size_t)t * Dn;
    float4 v[3];
#pragma unroll
    for (int i = 0; i < 3; i++) v[i] = *(const float4*)(row + (i * 64 + lane) * 4);
    float s = 0.f;
#pragma unroll
    for (int i = 0; i < 3; i++) s += (v[i].x + v[i].y) + (v[i].z + v[i].w);
#pragma unroll
    for (int off = 32; off >= 1; off >>= 1) s += __shfl_xor(s, off, 64);
    float mean = s * (1.0f / 768.0f);
    float s2 = 0.f;
#pragma unroll
    for (int i = 0; i < 3; i++) {
      float a = v[i].x - mean, b = v[i].y - mean, c = v[i].z - mean, d = v[i].w - mean;
      s2 += (a * a + b * b) + (c * c + d * d);
    }
#pragma unroll
    for (int off = 32; off >= 1; off >>= 1) s2 += __shfl_xor(s2, off, 64);
    float rstd = rsqrtf(s2 * (1.0f / 768.0f) + 1e-5f);
#pragma unroll
    for (int i = 0; i < 3; i++) {
      int d0 = (i * 64 + lane) * 4;
      float4 gv = *(const float4*)(g1 + d0);
      float4 bv = *(const float4*)(be1 + d0);
      ushort4 o;
      o.x = f2bf((v[i].x - mean) * rstd * gv.x + bv.x);
      o.y = f2bf((v[i].y - mean) * rstd * gv.y + bv.y);
      o.z = f2bf((v[i].z - mean) * rstd * gv.z + bv.z);
      o.w = f2bf((v[i].w - mean) * rstd * gv.w + bv.w);
      *(ushort4*)(hb + (size_t)t * Dn + d0) = o;
    }
  }
}

// ---- kernel 1: FUSED per-(b,h) QKV projection + flash attention ---------------
// r23 EXACT (verified). 384 blocks x 256 thr. LDS 152KB.
__global__ __launch_bounds__(256) void k_fused(
    const ushort_t* __restrict__ hb,  // [NT][768] bf16
    const ushort_t* __restrict__ Wc,  // [12][192][64] bf16
    const float* __restrict__ bc,     // [12][192] fp32
    const float* __restrict__ x,
    float* __restrict__ out1)
{
  __shared__ __align__(16) ushort_t smem[77824];   // 152KB
  ushort_t* Qs  = smem;
  ushort_t* Ks  = smem + 16384;
  ushort_t* Vts = smem + 32768;
  ushort_t* As  = smem + 49152;
  ushort_t* Ws  = smem + 65536;
  ushort_t* Pw  = smem + 49152;      // overlays As/Ws (dead after phase 1)

  const int bh = blockIdx.x;
  const int b_ = bh / Hn, h_ = bh - b_ * Hn;
  const int tid = threadIdx.x;
  const int wave = tid >> 6, lane = tid & 63;
  const int lrow = lane & 15, quad = lane >> 4;
  const int key = lrow & 7;          // 128B-row swizzle key (r15 derivation)
  const int t0 = b_ * Sn;

  { // stage As (256x64, 8 DMA/thr) + Ws (192x64, 6 DMA/thr), swizzled source
    const ushort_t* ga = hb + (size_t)t0 * Dn + h_ * 64;
#pragma unroll
    for (int j = 0; j < 8; ++j) {
      int q = j * 256 + tid;               // chunk 0..2047
      int row = q >> 3;
      int sc = (q & 7) ^ (row & 7);
      async_cp16(ga + (size_t)row * Dn + sc * 8, As + q * 8);
    }
    const ushort_t* gw = Wc + h_ * 12288;
#pragma unroll
    for (int j = 0; j < 6; ++j) {
      int q = j * 256 + tid;               // chunk 0..1535
      int row = q >> 3;
      int sc = (q & 7) ^ (row & 7);
      async_cp16(gw + row * 64 + sc * 8, Ws + q * 8);
    }
  }
  asm volatile("s_waitcnt vmcnt(0)" ::: "memory");
  __syncthreads();

  // ---- phase 1: QKV projection (old k_qkv wave layout, 2 row-halves) ----
  const int wm = (wave >> 1) * 64, wn = (wave & 1) * 96;
  for (int half = 0; half < 2; ++half) {
    f32x4 acc[4][6];
#pragma unroll
    for (int mi = 0; mi < 4; mi++)
#pragma unroll
      for (int ni = 0; ni < 6; ni++) acc[mi][ni] = (f32x4){0.f, 0.f, 0.f, 0.f};

#pragma unroll
    for (int kk = 0; kk < 2; kk++) {
      short8 af[4], wf[6];
#pragma unroll
      for (int mi = 0; mi < 4; mi++)
        af[mi] = *(const short8*)(As + (half * 128 + wm + mi * 16 + lrow) * 64 + ((((kk << 2) + quad)) ^ key) * 8);
#pragma unroll
      for (int ni = 0; ni < 6; ni++)
        wf[ni] = *(const short8*)(Ws + (wn + ni * 16 + lrow) * 64 + ((((kk << 2) + quad)) ^ key) * 8);
#pragma unroll
      for (int mi = 0; mi < 4; mi++)
#pragma unroll
        for (int ni = 0; ni < 6; ni++)
          acc[mi][ni] = __builtin_amdgcn_mfma_f32_16x16x32_bf16(af[mi], wf[ni], acc[mi][ni], 0, 0, 0);
    }

    // epilogue: Q,K -> swizzled LDS; V -> transposed swizzled LDS
#pragma unroll
    for (int ni = 0; ni < 6; ni++) {
      int c = wn + ni * 16 + lrow;       // 0..191
      int mat = c >> 6, e = c & 63;
      float bb = bc[h_ * 192 + c];
      if (mat < 2) {
        ushort_t* dst = (mat == 0) ? Qs : Ks;
#pragma unroll
        for (int mi = 0; mi < 4; mi++) {
#pragma unroll
          for (int r = 0; r < 4; r++) {
            int srow = half * 128 + wm + mi * 16 + quad * 4 + r;
            dst[srow * 64 + (((e >> 3) ^ (srow & 7)) << 3) + (e & 7)] = f2bf(acc[mi][ni][r] + bb);
          }
        }
      } else {
#pragma unroll
        for (int mi = 0; mi < 4; mi++) {
          int c4 = half * 128 + wm + mi * 16 + quad * 4;   // s-col, %8 in {0,4}
          ushort4 pk;
          pk.x = f2bf(acc[mi][ni][0] + bb);
          pk.y = f2bf(acc[mi][ni][1] + bb);
          pk.z = f2bf(acc[mi][ni][2] + bb);
          pk.w = f2bf(acc[mi][ni][3] + bb);
          int cq = c4 >> 3;
          *(ushort4*)(Vts + e * 256 + ((cq ^ (e & 7)) << 3) + (c4 & 7)) = pk;
        }
      }
    }
  }
  __syncthreads();

  // ---- phase 2: per-wave flash attention, K/V resident, single-pass softmax
  ushort_t* Pme = Pw + wave * 4224;    // [16 rows][264] per wave
  for (int p = 0; p < 4; ++p) {
    const int s0 = wave * 64 + p * 16;
    short8 qf[2];
#pragma unroll
    for (int kk = 0; kk < 2; kk++)
      qf[kk] = *(const short8*)(Qs + (s0 + lrow) * 64 + ((((kk << 2) + quad)) ^ key) * 8);

    f32x4 sc[16];
#pragma unroll
    for (int ni = 0; ni < 16; ni++) sc[ni] = (f32x4){0.f, 0.f, 0.f, 0.f};
#pragma unroll
    for (int kk = 0; kk < 2; kk++) {
#pragma unroll
      for (int ni = 0; ni < 16; ni++) {
        short8 kf = *(const short8*)(Ks + (ni * 16 + lrow) * 64 + ((((kk << 2) + quad)) ^ key) * 8);
        sc[ni] = __builtin_amdgcn_mfma_f32_16x16x32_bf16(qf[kk], kf, sc[ni], 0, 0, 0);
      }
    }

    // single-pass softmax over all 256 keys (rows quad*4+r, k-col ni*16+lrow)
    float inv[4];
#pragma unroll
    for (int r = 0; r < 4; r++) {
      float m_ = sc[0][r];
#pragma unroll
      for (int ni = 1; ni < 16; ni++) m_ = fmaxf(m_, sc[ni][r]);
#pragma unroll
      for (int msk = 8; msk >= 1; msk >>= 1) m_ = fmaxf(m_, __shfl_xor(m_, msk, 64));
      float s_ = 0.f;
#pragma unroll
      for (int ni = 0; ni < 16; ni++) {
        float pv = __expf((sc[ni][r] - m_) * 0.125f);
        s_ += pv;
        Pme[(quad * 4 + r) * 264 + ni * 16 + lrow] = f2bf(pv);
      }
#pragma unroll
      for (int msk = 8; msk >= 1; msk >>= 1) s_ += __shfl_xor(s_, msk, 64);
      inv[r] = 1.0f / s_;
    }
    asm volatile("s_waitcnt lgkmcnt(0)" ::: "memory");
    __builtin_amdgcn_sched_barrier(0);

    // PV: of[et] (16 q-rows x 64 e-cols), K=256 in 8 slices
    f32x4 of[4];
#pragma unroll
    for (int et = 0; et < 4; et++) of[et] = (f32x4){0.f, 0.f, 0.f, 0.f};
#pragma unroll
    for (int ks = 0; ks < 8; ks++) {
      short8 pf = *(const short8*)(Pme + lrow * 264 + ks * 32 + quad * 8);
#pragma unroll
      for (int et = 0; et < 4; et++) {
        short8 vf = *(const short8*)(Vts + (et * 16 + lrow) * 256 + ((((ks << 2) + quad)) ^ key) * 8);
        of[et] = __builtin_amdgcn_mfma_f32_16x16x32_bf16(pf, vf, of[et], 0, 0, 0);
      }
    }

    const size_t obase = ((size_t)t0 + s0) * Dn + h_ * 64;
#pragma unroll
    for (int r = 0; r < 4; r++) {
      float rl = inv[r];
      int row = quad * 4 + r;
#pragma unroll
      for (int et = 0; et < 4; et++) {
        size_t idx = obase + (size_t)row * Dn + et * 16 + lrow;
        out1[idx] = of[et][r] * rl + x[idx];
      }
    }
  }
}

// ---------------- kernel 4: LN2, wave-per-token (4 tokens/block, no barriers) --
__global__ __launch_bounds__(256) void k_ln2(
    const float* __restrict__ in, const float* __restrict__ g2,
    const float* __restrict__ be2, ushort_t* __restrict__ h2)
{
  const int tid = threadIdx.x;
  const int wave = tid >> 6, lane = tid & 63;
  const int t = blockIdx.x * 4 + wave;
  const float* row = in + (size_t)t * Dn;
  float4 v[3];
#pragma unroll
  for (int i = 0; i < 3; i++) v[i] = *(const float4*)(row + (i * 64 + lane) * 4);
  float s = 0.f;
#pragma unroll
  for (int i = 0; i < 3; i++) s += (v[i].x + v[i].y) + (v[i].z + v[i].w);
#pragma unroll
  for (int off = 32; off >= 1; off >>= 1) s += __shfl_xor(s, off, 64);
  float mean = s * (1.0f / 768.0f);
  float s2 = 0.f;
#pragma unroll
  for (int i = 0; i < 3; i++) {
    float a = v[i].x - mean, b = v[i].y - mean, c = v[i].z - mean, d = v[i].w - mean;
    s2 += (a * a + b * b) + (c * c + d * d);
  }
#pragma unroll
  for (int off = 32; off >= 1; off >>= 1) s2 += __shfl_xor(s2, off, 64);
  float rstd = rsqrtf(s2 * (1.0f / 768.0f) + 1e-5f);
#pragma unroll
  for (int i = 0; i < 3; i++) {
    int d0 = (i * 64 + lane) * 4;
    float4 gv = *(const float4*)(g2 + d0);
    float4 bv = *(const float4*)(be2 + d0);
    ushort4 o;
    o.x = f2bf((v[i].x - mean) * rstd * gv.x + bv.x);
    o.y = f2bf((v[i].y - mean) * rstd * gv.y + bv.y);
    o.z = f2bf((v[i].z - mean) * rstd * gv.z + bv.z);
    o.w = f2bf((v[i].w - mean) * rstd * gv.w + bv.w);
    *(ushort4*)(h2 + (size_t)t * Dn + d0) = o;
  }
}

// ---- kernel 5: fc1 MFMA GEMM, 256x192 tile, BK=64, 4-phase, grid 512 ----------
// r20 EXACT (63.5us / 43MB verified). gemm1 is schedule-saturated here (r24).
__global__ __launch_bounds__(512, 2) void k_gemm1(
    const ushort_t* __restrict__ A,   // h2 [8192][768] bf16
    const ushort_t* __restrict__ Bw,  // W1b [3072][768] bf16
    const float* __restrict__ bias,   // bm1 [3072]
    ushort_t* __restrict__ CoutB)     // mb [8192][3072] bf16
{
  constexpr int KD = Dn;              // 768
  constexpr int NTILES = 12;          // 768/64
  constexpr int BUFU = 28672;         // ushorts per buffer: A 16384 + B 12288
  __shared__ __align__(16) ushort_t smem[57344];   // 112KB
  const int b = blockIdx.x;
  const int xcd = b & 7, slot = b >> 3;   // 64 slots per XCD (512 = 8*64)
  const int cc = slot % 16, rloc = slot / 16;      // 16 col-tiles, 4 row-tiles
  const int m0 = (xcd * 4 + rloc) * 256, n0 = cc * 192;
  const int tid = threadIdx.x;
  const int wave = tid >> 6, lane = tid & 63;
  const int wm2 = (wave >> 2) * 128, wn2 = (wave & 3) * 48;
  const int lrow = lane & 15, quad = lane >> 4;
  const int key = lrow & 7;           // ds_read chunk XOR key (row&7 == lrow&7)

  f32x4 acc[8][3];
#pragma unroll
  for (int mi = 0; mi < 8; mi++)
#pragma unroll
    for (int ni = 0; ni < 3; ni++) acc[mi][ni] = (f32x4){0.f, 0.f, 0.f, 0.f};

  auto stageA = [&](int t, int half) {
    if (t >= NTILES) return;
    const int k0 = t * 64;
    ushort_t* tb = smem + (t & 1) * BUFU + half * 8192;
#pragma unroll
    for (int j = 0; j < 2; ++j) {
      int q = j * 512 + tid;                 // chunk 0..1023
      int row = q >> 3;
      int sc = (q & 7) ^ (row & 7);          // pre-swizzled global chunk
      async_cp16(A + (size_t)(m0 + half * 128 + row) * KD + k0 + sc * 8, tb + q * 8);
    }
  };
  auto stageB = [&](int t) {
    if (t >= NTILES) return;
    const int k0 = t * 64;
    ushort_t* tb = smem + (t & 1) * BUFU + 16384;
#pragma unroll
    for (int j = 0; j < 3; ++j) {
      int q = j * 512 + tid;                 // chunk 0..1535
      int row = q >> 3;
      int sc = (q & 7) ^ (row & 7);
      async_cp16(Bw + (size_t)(n0 + row) * KD + k0 + sc * 8, tb + q * 8);
    }
  };

  stageA(0, 0); stageA(0, 1); stageB(0);
  asm volatile("s_waitcnt vmcnt(0)" ::: "memory");
  __builtin_amdgcn_s_barrier();
  __builtin_amdgcn_sched_barrier(0);

  short8 af[4][2], af2[4][2], bf0[3], bf1[3];
  for (int t = 0; t < NTILES; ++t) {
    const ushort_t* Ab = smem + (t & 1) * BUFU;
    const ushort_t* Bb = Ab + 16384;

    // ---- ph0: read af-lo(both kk) + bf(kk0); stage A-lo(t+1); MFMA lo x kk0
#pragma unroll
    for (int mi = 0; mi < 4; ++mi)
#pragma unroll
      for (int kk = 0; kk < 2; ++kk)
        af[mi][kk] = *(const short8*)(Ab + (wm2 + mi * 16 + lrow) * 64 + (((kk << 2) + quad) ^ key) * 8);
#pragma unroll
    for (int ni = 0; ni < 3; ++ni)
      bf0[ni] = *(const short8*)(Bb + (wn2 + ni * 16 + lrow) * 64 + ((quad ^ key) * 8));
    stageA(t + 1, 0);
    __builtin_amdgcn_s_barrier();
    asm volatile("s_waitcnt lgkmcnt(0)" ::: "memory");
    __builtin_amdgcn_sched_barrier(0);
    __builtin_amdgcn_s_setprio(1);
#pragma unroll
    for (int mi = 0; mi < 4; ++mi)
#pragma unroll
      for (int ni = 0; ni < 3; ++ni)
        acc[mi][ni] = __builtin_amdgcn_mfma_f32_16x16x32_bf16(af[mi][0], bf0[ni], acc[mi][ni], 0, 0, 0);
    __builtin_amdgcn_s_setprio(0);
    __builtin_amdgcn_s_barrier();
    __builtin_amdgcn_sched_barrier(0);

    // ---- ph1: read bf(kk1) + af-hi(both kk); stage A-hi(t+1); MFMA lo x kk1
#pragma unroll
    for (int ni = 0; ni < 3; ++ni)
      bf1[ni] = *(const short8*)(Bb + (wn2 + ni * 16 + lrow) * 64 + (((4 + quad) ^ key) * 8));
#pragma unroll
    for (int mi = 0; mi < 4; ++mi)
#pragma unroll
      for (int kk = 0; kk < 2; ++kk)
        af2[mi][kk] = *(const short8*)(Ab + (wm2 + 64 + mi * 16 + lrow) * 64 + (((kk << 2) + quad) ^ key) * 8);
    stageA(t + 1, 1);
    __builtin_amdgcn_s_barrier();
    asm volatile("s_waitcnt lgkmcnt(0)" ::: "memory");
    __builtin_amdgcn_sched_barrier(0);
    __builtin_amdgcn_s_setprio(1);
#pragma unroll
    for (int mi = 0; mi < 4; ++mi)
#pragma unroll
      for (int ni = 0; ni < 3; ++ni)
        acc[mi][ni] = __builtin_amdgcn_mfma_f32_16x16x32_bf16(af[mi][1], bf1[ni], acc[mi][ni], 0, 0, 0);
    __builtin_amdgcn_s_setprio(0);
    __builtin_amdgcn_s_barrier();
    __builtin_amdgcn_sched_barrier(0);

    // ---- ph2: stage B(t+1); MFMA hi x kk0
    stageB(t + 1);
    __builtin_amdgcn_s_barrier();
    __builtin_amdgcn_sched_barrier(0);
    __builtin_amdgcn_s_setprio(1);
#pragma unroll
    for (int mi = 0; mi < 4; ++mi)
#pragma unroll
      for (int ni = 0; ni < 3; ++ni)
        acc[4 + mi][ni] = __builtin_amdgcn_mfma_f32_16x16x32_bf16(af2[mi][0], bf0[ni], acc[4 + mi][ni], 0, 0, 0);
    __builtin_amdgcn_s_setprio(0);
    __builtin_amdgcn_s_barrier();
    __builtin_amdgcn_sched_barrier(0);

    // ---- ph3: MFMA hi x kk1; drain t+1 stages; close tile
    __builtin_amdgcn_s_setprio(1);
#pragma unroll
    for (int mi = 0; mi < 4; ++mi)
#pragma unroll
      for (int ni = 0; ni < 3; ++ni)
        acc[4 + mi][ni] = __builtin_amdgcn_mfma_f32_16x16x32_bf16(af2[mi][1], bf1[ni], acc[4 + mi][ni], 0, 0, 0);
    __builtin_amdgcn_s_setprio(0);
    asm volatile("s_waitcnt vmcnt(0)" ::: "memory");
    __builtin_amdgcn_s_barrier();
    __builtin_amdgcn_sched_barrier(0);
  }

  // ---- epilogue: GELU+bias -> Cs[256][stride 200] one pass -> 16B stores
  float bwv[3];
#pragma unroll
  for (int ni = 0; ni < 3; ++ni) bwv[ni] = bias[n0 + wn2 + ni * 16 + lrow];
  __syncthreads();
#pragma unroll
  for (int mi = 0; mi < 8; ++mi) {
#pragma unroll
    for (int ni = 0; ni < 3; ++ni) {
      int col = wn2 + ni * 16 + lrow;
#pragma unroll
      for (int r = 0; r < 4; ++r) {
        int row = wm2 + mi * 16 + quad * 4 + r;
        float vv = acc[mi][ni][r] + bwv[ni];
        float u = vv * (0.7978845608f + 0.0356774081f * vv * vv);
        float o = vv / (1.0f + __expf(-2.0f * u));
        smem[row * 200 + col] = f2bf(o);
      }
    }
  }
  __syncthreads();
#pragma unroll
  for (int i = 0; i < 12; ++i) {
    int idx = i * 512 + tid;            // 0..6143 = 256 rows x 24 chunks
    int rr = idx / 24, ck = idx - rr * 24;
    const uint4 v = *(const uint4*)(smem + rr * 200 + ck * 8);
    *(uint4*)(CoutB + (size_t)(m0 + rr) * MLPn + n0 + ck * 8) = v;
  }
}

// ---- kernel 6: fc2 MFMA GEMM, 128x192 tile, BK=64, 3-buf 1-barrier/tile -------
// r22 EXACT (win verified).
__global__ __launch_bounds__(512, 2) void k_gemm2(
    const ushort_t* __restrict__ A,   // mb [8192][3072] bf16
    const ushort_t* __restrict__ Bw,  // W2b [768][3072] bf16
    const float* __restrict__ bias,   // bm2 [768]
    const float* __restrict__ res,    // out1 [8192][768] fp32
    float* __restrict__ out)          // d_out [8192][768] fp32
{
  constexpr int KD = MLPn;            // 3072
  constexpr int N = Dn;               // 768
  constexpr int NTILES = 48;          // 3072/64
  constexpr int BUFU = 20480;         // ushorts/buffer: A 8192 + B 12288
  __shared__ __align__(16) ushort_t smem[61440];   // 120KB (3 buffers)
  const int b = blockIdx.x;
  const int xcd = b & 7, slot = b >> 3;   // 32 slots per XCD (256 = 8*32)
  const int cc = slot & 3, rloc = slot >> 2;       // 4 col-tiles, 8 row-bands
  const int m0 = (xcd * 8 + rloc) * 128, n0 = cc * 192;
  const int tid = threadIdx.x;
  const int wave = tid >> 6, lane = tid & 63;
  const int wm2 = (wave >> 2) * 64, wn2 = (wave & 3) * 48;
  const int lrow = lane & 15, quad = lane >> 4;
  const int key = lrow & 7;           // 128B rows: key=row&7

  f32x4 acc[4][3];
#pragma unroll
  for (int mi = 0; mi < 4; mi++)
#pragma unroll
    for (int ni = 0; ni < 3; ni++) acc[mi][ni] = (f32x4){0.f, 0.f, 0.f, 0.f};

  auto stageT = [&](int t) {
    if (t >= NTILES) return;
    const int k0 = t * 64;
    ushort_t* bufA = smem + (t % 3) * BUFU;
    ushort_t* bufB = bufA + 8192;
#pragma unroll
    for (int j = 0; j < 2; ++j) {        // A: 128 rows x 8 chunks = 1024
      int q = j * 512 + tid;
      int row = q >> 3;
      int sc = (q & 7) ^ (row & 7);
      async_cp16(A + (size_t)(m0 + row) * KD + k0 + sc * 8, bufA + q * 8);
    }
#pragma unroll
    for (int j = 0; j < 3; ++j) {        // B: 192 rows x 8 chunks = 1536
      int q = j * 512 + tid;
      int row = q >> 3;
      int sc = (q & 7) ^ (row & 7);
      async_cp16(Bw + (size_t)(n0 + row) * KD + k0 + sc * 8, bufB + q * 8);
    }
  };

  stageT(0); stageT(1);
  asm volatile("s_waitcnt vmcnt(5)" ::: "memory");
  __builtin_amdgcn_s_barrier();
  __builtin_amdgcn_sched_barrier(0);

  short8 af[4], bf[3];
  for (int t = 0; t < NTILES; ++t) {
    const ushort_t* Ab = smem + (t % 3) * BUFU;
    const ushort_t* Bb = Ab + 8192;

#pragma unroll
    for (int mi = 0; mi < 4; ++mi)
      af[mi] = *(const short8*)(Ab + (wm2 + mi * 16 + lrow) * 64 + ((quad ^ key) * 8));
#pragma unroll
    for (int ni = 0; ni < 3; ++ni)
      bf[ni] = *(const short8*)(Bb + (wn2 + ni * 16 + lrow) * 64 + ((quad ^ key) * 8));
    stageT(t + 2);
    asm volatile("s_waitcnt lgkmcnt(0)" ::: "memory");
    __builtin_amdgcn_sched_barrier(0);
    __builtin_amdgcn_s_setprio(1);
#pragma unroll
    for (int mi = 0; mi < 4; ++mi)
#pragma unroll
      for (int ni = 0; ni < 3; ++ni)
        acc[mi][ni] = __builtin_amdgcn_mfma_f32_16x16x32_bf16(af[mi], bf[ni], acc[mi][ni], 0, 0, 0);
    __builtin_amdgcn_s_setprio(0);
#pragma unroll
    for (int mi = 0; mi < 4; ++mi)
      af[mi] = *(const short8*)(Ab + (wm2 + mi * 16 + lrow) * 64 + (((4 + quad) ^ key) * 8));
#pragma unroll
    for (int ni = 0; ni < 3; ++ni)
      bf[ni] = *(const short8*)(Bb + (wn2 + ni * 16 + lrow) * 64 + (((4 + quad) ^ key) * 8));
    asm volatile("s_waitcnt lgkmcnt(0)" ::: "memory");
    __builtin_amdgcn_sched_barrier(0);
    __builtin_amdgcn_s_setprio(1);
#pragma unroll
    for (int mi = 0; mi < 4; ++mi)
#pragma unroll
      for (int ni = 0; ni < 3; ++ni)
        acc[mi][ni] = __builtin_amdgcn_mfma_f32_16x16x32_bf16(af[mi], bf[ni], acc[mi][ni], 0, 0, 0);
    __builtin_amdgcn_s_setprio(0);
    if (t < NTILES - 2) {
      asm volatile("s_waitcnt vmcnt(5)" ::: "memory");
    } else {
      asm volatile("s_waitcnt vmcnt(0)" ::: "memory");
    }
    __builtin_amdgcn_s_barrier();
    __builtin_amdgcn_sched_barrier(0);
  }

  // fused epilogue: + bias + residual -> fp32 (16-lane x 4B = 64B segments)
#pragma unroll
  for (int ni = 0; ni < 3; ++ni) {
    int col = n0 + wn2 + ni * 16 + lrow;
    float bc = bias[col];
#pragma unroll
    for (int mi = 0; mi < 4; ++mi) {
#pragma unroll
      for (int r = 0; r < 4; ++r) {
        int row = m0 + wm2 + mi * 16 + quad * 4 + r;
        size_t idx = (size_t)row * N + col;
        out[idx] = acc[mi][ni][r] + bc + res[idx];
      }
    }
  }
}

// ---------------- launch --------------------------------------------------------
extern "C" void kernel_launch(void* const* d_in, const int* in_sizes, int n_in,
                              void* d_out, int out_size, void* d_ws, size_t ws_size,
                              hipStream_t stream) {
  (void)in_sizes; (void)n_in; (void)out_size; (void)ws_size;
  const float* x   = (const float*)d_in[0];
  const float* g1  = (const float*)d_in[1];
  const float* be1 = (const float*)d_in[2];
  const float* Wq  = (const float*)d_in[3];
  const float* bq  = (const float*)d_in[4];
  const float* Wk  = (const float*)d_in[5];
  const float* bk  = (const float*)d_in[6];
  const float* Wv  = (const float*)d_in[7];
  const float* bv  = (const float*)d_in[8];
  const float* g2  = (const float*)d_in[9];
  const float* be2 = (const float*)d_in[10];
  const float* W1  = (const float*)d_in[11];
  const float* bm1 = (const float*)d_in[12];
  const float* W2  = (const float*)d_in[13];
  const float* bm2 = (const float*)d_in[14];
  float* outp = (float*)d_out;

  char* ws = (char*)d_ws;
  float*    out1 = (float*)ws;                   // [0, 25165824)
  ushort_t* hb   = (ushort_t*)(ws + 25165824);   // pre-attn bf16
  ushort_t* h2   = (ushort_t*)(ws + 25165824);   // post-attn bf16 (overlays hb)
  ushort_t* mb   = (ushort_t*)(ws + 37748736);
  ushort_t* Wc   = (ushort_t*)(ws + 88080384);
  ushort_t* W1b  = (ushort_t*)(ws + 88375296);
  ushort_t* W2b  = (ushort_t*)(ws + 93093888);
  float*    bcb  = (float*)(ws + 97812480);

  k_prep<<<dim3(5184 + NT / 4), dim3(256), 0, stream>>>(Wq, Wk, Wv, bq, bk, bv, W1, W2,
                                                        x, g1, be1, Wc, bcb, W1b, W2b, hb);
  k_fused<<<dim3(Bn * Hn), dim3(256), 0, stream>>>(hb, Wc, bcb, x, out1);
  k_ln2<<<dim3(NT / 4), dim3(256), 0, stream>>>(out1, g2, be2, h2);
  k_gemm1<<<dim3(512), dim3(512), 0, stream>>>(h2, W1b, bm1, mb);
  k_gemm2<<<dim3(256), dim3(512), 0, stream>>>(mb, W2b, bm2, out1, outp);
}

// Round 12
// 261.823 us; speedup vs baseline: 1.0403x; 1.0006x over previous
//
#include <hip/hip_runtime.h>
#include <hip/hip_bf16.h>
#include <math.h>

// ViT block, B=32 S=256 D=768 H=12 HD=64 MLP=3072. fp32 I/O, bf16 MFMA inside.
//
// ws layout (r23 REMAP, total ~97.8 MB; peak live = gemm1 epoch 97.5MB):
//   [0,        25165824)  out1 fp32 [8192][768]  (residual trunk)
//   [25165824, 37748736)  hb bf16 (pre-attn) ; h2 bf16 (post-attn, overlays hb)
//   [37748736, 88080384)  mb bf16 [8192][3072] gelu(fc1)
//   [88080384, 88375296)  Wc  bf16 [12][192][64] packed qkv weights
//   [88375296, 93093888)  W1b bf16 [3072][768]
//   [93093888, 97812480)  W2b bf16 [768][3072]
//   [97812480, 97821696)  bcb fp32 [12][192] packed qkv bias
//
// Journal notes baked in:
//  - r13 WIN: XCD swizzle on GEMM grids. Keep.
//  - r15: both-sides XOR swizzle; KEY: 128B rows -> key=row&7; 64B rows ->
//    key=(row>>1)&3.
//  - r19 LESSON: launch_bounds 2nd arg caps regs; acc spill = catastrophe.
//  - r20 WIN: gemm1 256x192 BK=64 4-phase grid 512 -> 63.5us / 43MB.
//  - r22 WIN: gemm2 128x192 BK=64 3-buf 1-barrier/tile vmcnt(5).
//  - r23 WIN: fused QKV+attn (K/V LDS-resident, single-pass softmax).
//  - r24 CONFOUNDED: r22-port of gemm1 flat BUT it changed tile too
//    (FETCH 43->80MB canceled the sync win). Reverted.
//  - r25 WIN: wave-per-token LN (float4 x3, shfl_xor, 0 barriers) -> 262.0.
//  - r26 THIS ROUND: clean barrier ablation on gemm1. Audit: within a tile,
//    reads hit buf t&1, stages write buf (t+1)&1 -- DISJOINT, so 6 of 8
//    barriers/tile were pure lockstep pacing. Keep ONLY per-phase lgkm0+
//    sched_barrier (rule #18) and the end-of-tile {vmcnt(0); s_barrier}.
//    Tile/staging/swizzle/ledger byte-identical to r20. Sync edges 96->24.
//    Tripwire: flat => drain-bound, GEMM family at verified plateau.

static constexpr int Bn = 32, Sn = 256, Dn = 768, Hn = 12, HDn = 64, MLPn = 3072;
static constexpr int NT = Bn * Sn; // 8192 tokens

typedef unsigned short ushort_t;
typedef unsigned int u32;
typedef __attribute__((ext_vector_type(8))) short short8; // 8 bf16 MFMA A/B frag
typedef __attribute__((ext_vector_type(4))) float f32x4;  // MFMA C/D frag

__device__ __forceinline__ float bf2f(ushort_t u) { return __uint_as_float(((u32)u) << 16); }
__device__ __forceinline__ ushort_t f2bf(float f) { // round-to-nearest-even
  u32 u = __float_as_uint(f);
  u += 0x7fffu + ((u >> 16) & 1u);
  return (ushort_t)(u >> 16);
}

// async global->LDS 16B per lane; LDS dest = wave-uniform base + lane*16 (m97/m104)
__device__ __forceinline__ void async_cp16(const ushort_t* g, ushort_t* l) {
  __builtin_amdgcn_global_load_lds(
      (const __attribute__((address_space(1))) u32*)g,
      (__attribute__((address_space(3))) u32*)l, 16, 0, 0);
}

// ------- kernel 0: weight prep + LN1 in ONE launch (independent work) ----------
// blocks [0,576)      : pack Wq|Wk|Wv -> Wc bf16 + bias -> bcb
// blocks [576,5184)   : W1/W2 -> bf16
// blocks [5184,7232)  : LN1, wave-per-token (4 tokens/block, no barriers)
__global__ __launch_bounds__(256) void k_prep(
    const float* __restrict__ Wq, const float* __restrict__ Wk,
    const float* __restrict__ Wv, const float* __restrict__ bq,
    const float* __restrict__ bk, const float* __restrict__ bv,
    const float* __restrict__ W1, const float* __restrict__ W2,
    const float* __restrict__ x, const float* __restrict__ g1,
    const float* __restrict__ be1,
    ushort_t* __restrict__ Wc, float* __restrict__ bc,
    ushort_t* __restrict__ W1b, ushort_t* __restrict__ W2b,
    ushort_t* __restrict__ hb)
{
  const int bx = blockIdx.x;
  const int tid = threadIdx.x;
  if (bx < 576) {
    int i = bx * 256 + tid; // 0 .. 147455
    int h = i / 12288, rem = i - h * 12288;
    int mat = rem / 4096, w = rem - mat * 4096;
    const float* src = (mat == 0) ? Wq : ((mat == 1) ? Wk : Wv);
    Wc[i] = f2bf(src[h * 4096 + w]);
    if (i < Hn * 192) {
      int h2 = i / 192, r2 = i - h2 * 192;
      int m2 = r2 / 64, e2 = r2 - m2 * 64;
      const float* bs = (m2 == 0) ? bq : ((m2 == 1) ? bk : bv);
      bc[i] = bs[h2 * 64 + e2];
    }
  } else if (bx < 5184) {
    int j = bx - 576;
    const float* src = (j < 2304) ? W1 : W2;
    ushort_t* dst = (j < 2304) ? W1b : W2b;
    int i = (j % 2304) * 256 + tid; // float4 index < 589824
    float4 v = ((const float4*)src)[i];
    ushort4 o;
    o.x = f2bf(v.x); o.y = f2bf(v.y); o.z = f2bf(v.z); o.w = f2bf(v.w);
    ((ushort4*)dst)[i] = o;
  } else {
    // LN1: wave-per-token. 64 lanes x 3 float4 = 768 floats; no barriers.
    const int wave = tid >> 6, lane = tid & 63;
    const int t = (bx - 5184) * 4 + wave;
    const float* row = x + (size_t)t * Dn;
    float4 v[3];
#pragma unroll
    for (int i = 0; i < 3; i++) v[i] = *(const float4*)(row + (i * 64 + lane) * 4);
    float s = 0.f;
#pragma unroll
    for (int i = 0; i < 3; i++) s += (v[i].x + v[i].y) + (v[i].z + v[i].w);
#pragma unroll
    for (int off = 32; off >= 1; off >>= 1) s += __shfl_xor(s, off, 64);
    float mean = s * (1.0f / 768.0f);
    float s2 = 0.f;
#pragma unroll
    for (int i = 0; i < 3; i++) {
      float a = v[i].x - mean, b = v[i].y - mean, c = v[i].z - mean, d = v[i].w - mean;
      s2 += (a * a + b * b) + (c * c + d * d);
    }
#pragma unroll
    for (int off = 32; off >= 1; off >>= 1) s2 += __shfl_xor(s2, off, 64);
    float rstd = rsqrtf(s2 * (1.0f / 768.0f) + 1e-5f);
#pragma unroll
    for (int i = 0; i < 3; i++) {
      int d0 = (i * 64 + lane) * 4;
      float4 gv = *(const float4*)(g1 + d0);
      float4 bv = *(const float4*)(be1 + d0);
      ushort4 o;
      o.x = f2bf((v[i].x - mean) * rstd * gv.x + bv.x);
      o.y = f2bf((v[i].y - mean) * rstd * gv.y + bv.y);
      o.z = f2bf((v[i].z - mean) * rstd * gv.z + bv.z);
      o.w = f2bf((v[i].w - mean) * rstd * gv.w + bv.w);
      *(ushort4*)(hb + (size_t)t * Dn + d0) = o;
    }
  }
}

// ---- kernel 1: FUSED per-(b,h) QKV projection + flash attention ---------------
// r23 EXACT (verified). 384 blocks x 256 thr. LDS 152KB.
__global__ __launch_bounds__(256) void k_fused(
    const ushort_t* __restrict__ hb,  // [NT][768] bf16
    const ushort_t* __restrict__ Wc,  // [12][192][64] bf16
    const float* __restrict__ bc,     // [12][192] fp32
    const float* __restrict__ x,
    float* __restrict__ out1)
{
  __shared__ __align__(16) ushort_t smem[77824];   // 152KB
  ushort_t* Qs  = smem;
  ushort_t* Ks  = smem + 16384;
  ushort_t* Vts = smem + 32768;
  ushort_t* As  = smem + 49152;
  ushort_t* Ws  = smem + 65536;
  ushort_t* Pw  = smem + 49152;      // overlays As/Ws (dead after phase 1)

  const int bh = blockIdx.x;
  const int b_ = bh / Hn, h_ = bh - b_ * Hn;
  const int tid = threadIdx.x;
  const int wave = tid >> 6, lane = tid & 63;
  const int lrow = lane & 15, quad = lane >> 4;
  const int key = lrow & 7;          // 128B-row swizzle key (r15 derivation)
  const int t0 = b_ * Sn;

  { // stage As (256x64, 8 DMA/thr) + Ws (192x64, 6 DMA/thr), swizzled source
    const ushort_t* ga = hb + (size_t)t0 * Dn + h_ * 64;
#pragma unroll
    for (int j = 0; j < 8; ++j) {
      int q = j * 256 + tid;               // chunk 0..2047
      int row = q >> 3;
      int sc = (q & 7) ^ (row & 7);
      async_cp16(ga + (size_t)row * Dn + sc * 8, As + q * 8);
    }
    const ushort_t* gw = Wc + h_ * 12288;
#pragma unroll
    for (int j = 0; j < 6; ++j) {
      int q = j * 256 + tid;               // chunk 0..1535
      int row = q >> 3;
      int sc = (q & 7) ^ (row & 7);
      async_cp16(gw + row * 64 + sc * 8, Ws + q * 8);
    }
  }
  asm volatile("s_waitcnt vmcnt(0)" ::: "memory");
  __syncthreads();

  // ---- phase 1: QKV projection (old k_qkv wave layout, 2 row-halves) ----
  const int wm = (wave >> 1) * 64, wn = (wave & 1) * 96;
  for (int half = 0; half < 2; ++half) {
    f32x4 acc[4][6];
#pragma unroll
    for (int mi = 0; mi < 4; mi++)
#pragma unroll
      for (int ni = 0; ni < 6; ni++) acc[mi][ni] = (f32x4){0.f, 0.f, 0.f, 0.f};

#pragma unroll
    for (int kk = 0; kk < 2; kk++) {
      short8 af[4], wf[6];
#pragma unroll
      for (int mi = 0; mi < 4; mi++)
        af[mi] = *(const short8*)(As + (half * 128 + wm + mi * 16 + lrow) * 64 + ((((kk << 2) + quad)) ^ key) * 8);
#pragma unroll
      for (int ni = 0; ni < 6; ni++)
        wf[ni] = *(const short8*)(Ws + (wn + ni * 16 + lrow) * 64 + ((((kk << 2) + quad)) ^ key) * 8);
#pragma unroll
      for (int mi = 0; mi < 4; mi++)
#pragma unroll
        for (int ni = 0; ni < 6; ni++)
          acc[mi][ni] = __builtin_amdgcn_mfma_f32_16x16x32_bf16(af[mi], wf[ni], acc[mi][ni], 0, 0, 0);
    }

    // epilogue: Q,K -> swizzled LDS; V -> transposed swizzled LDS
#pragma unroll
    for (int ni = 0; ni < 6; ni++) {
      int c = wn + ni * 16 + lrow;       // 0..191
      int mat = c >> 6, e = c & 63;
      float bb = bc[h_ * 192 + c];
      if (mat < 2) {
        ushort_t* dst = (mat == 0) ? Qs : Ks;
#pragma unroll
        for (int mi = 0; mi < 4; mi++) {
#pragma unroll
          for (int r = 0; r < 4; r++) {
            int srow = half * 128 + wm + mi * 16 + quad * 4 + r;
            dst[srow * 64 + (((e >> 3) ^ (srow & 7)) << 3) + (e & 7)] = f2bf(acc[mi][ni][r] + bb);
          }
        }
      } else {
#pragma unroll
        for (int mi = 0; mi < 4; mi++) {
          int c4 = half * 128 + wm + mi * 16 + quad * 4;   // s-col, %8 in {0,4}
          ushort4 pk;
          pk.x = f2bf(acc[mi][ni][0] + bb);
          pk.y = f2bf(acc[mi][ni][1] + bb);
          pk.z = f2bf(acc[mi][ni][2] + bb);
          pk.w = f2bf(acc[mi][ni][3] + bb);
          int cq = c4 >> 3;
          *(ushort4*)(Vts + e * 256 + ((cq ^ (e & 7)) << 3) + (c4 & 7)) = pk;
        }
      }
    }
  }
  __syncthreads();

  // ---- phase 2: per-wave flash attention, K/V resident, single-pass softmax
  ushort_t* Pme = Pw + wave * 4224;    // [16 rows][264] per wave
  for (int p = 0; p < 4; ++p) {
    const int s0 = wave * 64 + p * 16;
    short8 qf[2];
#pragma unroll
    for (int kk = 0; kk < 2; kk++)
      qf[kk] = *(const short8*)(Qs + (s0 + lrow) * 64 + ((((kk << 2) + quad)) ^ key) * 8);

    f32x4 sc[16];
#pragma unroll
    for (int ni = 0; ni < 16; ni++) sc[ni] = (f32x4){0.f, 0.f, 0.f, 0.f};
#pragma unroll
    for (int kk = 0; kk < 2; kk++) {
#pragma unroll
      for (int ni = 0; ni < 16; ni++) {
        short8 kf = *(const short8*)(Ks + (ni * 16 + lrow) * 64 + ((((kk << 2) + quad)) ^ key) * 8);
        sc[ni] = __builtin_amdgcn_mfma_f32_16x16x32_bf16(qf[kk], kf, sc[ni], 0, 0, 0);
      }
    }

    // single-pass softmax over all 256 keys (rows quad*4+r, k-col ni*16+lrow)
    float inv[4];
#pragma unroll
    for (int r = 0; r < 4; r++) {
      float m_ = sc[0][r];
#pragma unroll
      for (int ni = 1; ni < 16; ni++) m_ = fmaxf(m_, sc[ni][r]);
#pragma unroll
      for (int msk = 8; msk >= 1; msk >>= 1) m_ = fmaxf(m_, __shfl_xor(m_, msk, 64));
      float s_ = 0.f;
#pragma unroll
      for (int ni = 0; ni < 16; ni++) {
        float pv = __expf((sc[ni][r] - m_) * 0.125f);
        s_ += pv;
        Pme[(quad * 4 + r) * 264 + ni * 16 + lrow] = f2bf(pv);
      }
#pragma unroll
      for (int msk = 8; msk >= 1; msk >>= 1) s_ += __shfl_xor(s_, msk, 64);
      inv[r] = 1.0f / s_;
    }
    asm volatile("s_waitcnt lgkmcnt(0)" ::: "memory");
    __builtin_amdgcn_sched_barrier(0);

    // PV: of[et] (16 q-rows x 64 e-cols), K=256 in 8 slices
    f32x4 of[4];
#pragma unroll
    for (int et = 0; et < 4; et++) of[et] = (f32x4){0.f, 0.f, 0.f, 0.f};
#pragma unroll
    for (int ks = 0; ks < 8; ks++) {
      short8 pf = *(const short8*)(Pme + lrow * 264 + ks * 32 + quad * 8);
#pragma unroll
      for (int et = 0; et < 4; et++) {
        short8 vf = *(const short8*)(Vts + (et * 16 + lrow) * 256 + ((((ks << 2) + quad)) ^ key) * 8);
        of[et] = __builtin_amdgcn_mfma_f32_16x16x32_bf16(pf, vf, of[et], 0, 0, 0);
      }
    }

    const size_t obase = ((size_t)t0 + s0) * Dn + h_ * 64;
#pragma unroll
    for (int r = 0; r < 4; r++) {
      float rl = inv[r];
      int row = quad * 4 + r;
#pragma unroll
      for (int et = 0; et < 4; et++) {
        size_t idx = obase + (size_t)row * Dn + et * 16 + lrow;
        out1[idx] = of[et][r] * rl + x[idx];
      }
    }
  }
}

// ---------------- kernel 4: LN2, wave-per-token (4 tokens/block, no barriers) --
__global__ __launch_bounds__(256) void k_ln2(
    const float* __restrict__ in, const float* __restrict__ g2,
    const float* __restrict__ be2, ushort_t* __restrict__ h2)
{
  const int tid = threadIdx.x;
  const int wave = tid >> 6, lane = tid & 63;
  const int t = blockIdx.x * 4 + wave;
  const float* row = in + (size_t)t * Dn;
  float4 v[3];
#pragma unroll
  for (int i = 0; i < 3; i++) v[i] = *(const float4*)(row + (i * 64 + lane) * 4);
  float s = 0.f;
#pragma unroll
  for (int i = 0; i < 3; i++) s += (v[i].x + v[i].y) + (v[i].z + v[i].w);
#pragma unroll
  for (int off = 32; off >= 1; off >>= 1) s += __shfl_xor(s, off, 64);
  float mean = s * (1.0f / 768.0f);
  float s2 = 0.f;
#pragma unroll
  for (int i = 0; i < 3; i++) {
    float a = v[i].x - mean, b = v[i].y - mean, c = v[i].z - mean, d = v[i].w - mean;
    s2 += (a * a + b * b) + (c * c + d * d);
  }
#pragma unroll
  for (int off = 32; off >= 1; off >>= 1) s2 += __shfl_xor(s2, off, 64);
  float rstd = rsqrtf(s2 * (1.0f / 768.0f) + 1e-5f);
#pragma unroll
  for (int i = 0; i < 3; i++) {
    int d0 = (i * 64 + lane) * 4;
    float4 gv = *(const float4*)(g2 + d0);
    float4 bv = *(const float4*)(be2 + d0);
    ushort4 o;
    o.x = f2bf((v[i].x - mean) * rstd * gv.x + bv.x);
    o.y = f2bf((v[i].y - mean) * rstd * gv.y + bv.y);
    o.z = f2bf((v[i].z - mean) * rstd * gv.z + bv.z);
    o.w = f2bf((v[i].w - mean) * rstd * gv.w + bv.w);
    *(ushort4*)(h2 + (size_t)t * Dn + d0) = o;
  }
}

// ---- kernel 5: fc1 MFMA GEMM, 256x192 tile, BK=64, grid 512 -------------------
// r26: r20's exact tile/staging/swizzle/ledger, with the 6 DEAD barriers per
// tile removed (reads hit buf t&1, stages write buf (t+1)&1 -- disjoint).
// Kept: per-phase lgkmcnt(0)+sched_barrier before MFMA (rule #18), end-of-tile
// {vmcnt(0); s_barrier} (buffer-complete + WAR). Sync edges 96 -> 24.
__global__ __launch_bounds__(512, 2) void k_gemm1(
    const ushort_t* __restrict__ A,   // h2 [8192][768] bf16
    const ushort_t* __restrict__ Bw,  // W1b [3072][768] bf16
    const float* __restrict__ bias,   // bm1 [3072]
    ushort_t* __restrict__ CoutB)     // mb [8192][3072] bf16
{
  constexpr int KD = Dn;              // 768
  constexpr int NTILES = 12;          // 768/64
  constexpr int BUFU = 28672;         // ushorts per buffer: A 16384 + B 12288
  __shared__ __align__(16) ushort_t smem[57344];   // 112KB
  const int b = blockIdx.x;
  const int xcd = b & 7, slot = b >> 3;   // 64 slots per XCD (512 = 8*64)
  const int cc = slot % 16, rloc = slot / 16;      // 16 col-tiles, 4 row-tiles
  const int m0 = (xcd * 4 + rloc) * 256, n0 = cc * 192;
  const int tid = threadIdx.x;
  const int wave = tid >> 6, lane = tid & 63;
  const int wm2 = (wave >> 2) * 128, wn2 = (wave & 3) * 48;
  const int lrow = lane & 15, quad = lane >> 4;
  const int key = lrow & 7;           // ds_read chunk XOR key (row&7 == lrow&7)

  f32x4 acc[8][3];
#pragma unroll
  for (int mi = 0; mi < 8; mi++)
#pragma unroll
    for (int ni = 0; ni < 3; ni++) acc[mi][ni] = (f32x4){0.f, 0.f, 0.f, 0.f};

  auto stageA = [&](int t, int half) {
    if (t >= NTILES) return;
    const int k0 = t * 64;
    ushort_t* tb = smem + (t & 1) * BUFU + half * 8192;
#pragma unroll
    for (int j = 0; j < 2; ++j) {
      int q = j * 512 + tid;                 // chunk 0..1023
      int row = q >> 3;
      int sc = (q & 7) ^ (row & 7);          // pre-swizzled global chunk
      async_cp16(A + (size_t)(m0 + half * 128 + row) * KD + k0 + sc * 8, tb + q * 8);
    }
  };
  auto stageB = [&](int t) {
    if (t >= NTILES) return;
    const int k0 = t * 64;
    ushort_t* tb = smem + (t & 1) * BUFU + 16384;
#pragma unroll
    for (int j = 0; j < 3; ++j) {
      int q = j * 512 + tid;                 // chunk 0..1535
      int row = q >> 3;
      int sc = (q & 7) ^ (row & 7);
      async_cp16(Bw + (size_t)(n0 + row) * KD + k0 + sc * 8, tb + q * 8);
    }
  };

  stageA(0, 0); stageA(0, 1); stageB(0);
  asm volatile("s_waitcnt vmcnt(0)" ::: "memory");
  __builtin_amdgcn_s_barrier();
  __builtin_amdgcn_sched_barrier(0);

  short8 af[4][2], af2[4][2], bf0[3], bf1[3];
  for (int t = 0; t < NTILES; ++t) {
    const ushort_t* Ab = smem + (t & 1) * BUFU;
    const ushort_t* Bb = Ab + 16384;

    // ---- ph0: read af-lo(both kk) + bf(kk0); stage A-lo(t+1); MFMA lo x kk0
#pragma unroll
    for (int mi = 0; mi < 4; ++mi)
#pragma unroll
      for (int kk = 0; kk < 2; ++kk)
        af[mi][kk] = *(const short8*)(Ab + (wm2 + mi * 16 + lrow) * 64 + (((kk << 2) + quad) ^ key) * 8);
#pragma unroll
    for (int ni = 0; ni < 3; ++ni)
      bf0[ni] = *(const short8*)(Bb + (wn2 + ni * 16 + lrow) * 64 + ((quad ^ key) * 8));
    stageA(t + 1, 0);
    asm volatile("s_waitcnt lgkmcnt(0)" ::: "memory");
    __builtin_amdgcn_sched_barrier(0);
    __builtin_amdgcn_s_setprio(1);
#pragma unroll
    for (int mi = 0; mi < 4; ++mi)
#pragma unroll
      for (int ni = 0; ni < 3; ++ni)
        acc[mi][ni] = __builtin_amdgcn_mfma_f32_16x16x32_bf16(af[mi][0], bf0[ni], acc[mi][ni], 0, 0, 0);
    __builtin_amdgcn_s_setprio(0);

    // ---- ph1: read bf(kk1) + af-hi(both kk); stage A-hi(t+1); MFMA lo x kk1
#pragma unroll
    for (int ni = 0; ni < 3; ++ni)
      bf1[ni] = *(const short8*)(Bb + (wn2 + ni * 16 + lrow) * 64 + (((4 + quad) ^ key) * 8));
#pragma unroll
    for (int mi = 0; mi < 4; ++mi)
#pragma unroll
      for (int kk = 0; kk < 2; ++kk)
        af2[mi][kk] = *(const short8*)(Ab + (wm2 + 64 + mi * 16 + lrow) * 64 + (((kk << 2) + quad) ^ key) * 8);
    stageA(t + 1, 1);
    asm volatile("s_waitcnt lgkmcnt(0)" ::: "memory");
    __builtin_amdgcn_sched_barrier(0);
    __builtin_amdgcn_s_setprio(1);
#pragma unroll
    for (int mi = 0; mi < 4; ++mi)
#pragma unroll
      for (int ni = 0; ni < 3; ++ni)
        acc[mi][ni] = __builtin_amdgcn_mfma_f32_16x16x32_bf16(af[mi][1], bf1[ni], acc[mi][ni], 0, 0, 0);
    __builtin_amdgcn_s_setprio(0);

    // ---- ph2: stage B(t+1); MFMA hi x kk0 (frags already in regs)
    stageB(t + 1);
    __builtin_amdgcn_s_setprio(1);
#pragma unroll
    for (int mi = 0; mi < 4; ++mi)
#pragma unroll
      for (int ni = 0; ni < 3; ++ni)
        acc[4 + mi][ni] = __builtin_amdgcn_mfma_f32_16x16x32_bf16(af2[mi][0], bf0[ni], acc[4 + mi][ni], 0, 0, 0);
    __builtin_amdgcn_s_setprio(0);

    // ---- ph3: MFMA hi x kk1; drain t+1 stages; single tile barrier
    __builtin_amdgcn_s_setprio(1);
#pragma unroll
    for (int mi = 0; mi < 4; ++mi)
#pragma unroll
      for (int ni = 0; ni < 3; ++ni)
        acc[4 + mi][ni] = __builtin_amdgcn_mfma_f32_16x16x32_bf16(af2[mi][1], bf1[ni], acc[4 + mi][ni], 0, 0, 0);
    __builtin_amdgcn_s_setprio(0);
    asm volatile("s_waitcnt vmcnt(0)" ::: "memory");
    __builtin_amdgcn_s_barrier();
    __builtin_amdgcn_sched_barrier(0);
  }

  // ---- epilogue: GELU+bias -> Cs[256][stride 200] one pass -> 16B stores
  float bwv[3];
#pragma unroll
  for (int ni = 0; ni < 3; ++ni) bwv[ni] = bias[n0 + wn2 + ni * 16 + lrow];
  __syncthreads();
#pragma unroll
  for (int mi = 0; mi < 8; ++mi) {
#pragma unroll
    for (int ni = 0; ni < 3; ++ni) {
      int col = wn2 + ni * 16 + lrow;
#pragma unroll
      for (int r = 0; r < 4; ++r) {
        int row = wm2 + mi * 16 + quad * 4 + r;
        float vv = acc[mi][ni][r] + bwv[ni];
        float u = vv * (0.7978845608f + 0.0356774081f * vv * vv);
        float o = vv / (1.0f + __expf(-2.0f * u));
        smem[row * 200 + col] = f2bf(o);
      }
    }
  }
  __syncthreads();
#pragma unroll
  for (int i = 0; i < 12; ++i) {
    int idx = i * 512 + tid;            // 0..6143 = 256 rows x 24 chunks
    int rr = idx / 24, ck = idx - rr * 24;
    const uint4 v = *(const uint4*)(smem + rr * 200 + ck * 8);
    *(uint4*)(CoutB + (size_t)(m0 + rr) * MLPn + n0 + ck * 8) = v;
  }
}

// ---- kernel 6: fc2 MFMA GEMM, 128x192 tile, BK=64, 3-buf 1-barrier/tile -------
// r22 EXACT (win verified).
__global__ __launch_bounds__(512, 2) void k_gemm2(
    const ushort_t* __restrict__ A,   // mb [8192][3072] bf16
    const ushort_t* __restrict__ Bw,  // W2b [768][3072] bf16
    const float* __restrict__ bias,   // bm2 [768]
    const float* __restrict__ res,    // out1 [8192][768] fp32
    float* __restrict__ out)          // d_out [8192][768] fp32
{
  constexpr int KD = MLPn;            // 3072
  constexpr int N = Dn;               // 768
  constexpr int NTILES = 48;          // 3072/64
  constexpr int BUFU = 20480;         // ushorts/buffer: A 8192 + B 12288
  __shared__ __align__(16) ushort_t smem[61440];   // 120KB (3 buffers)
  const int b = blockIdx.x;
  const int xcd = b & 7, slot = b >> 3;   // 32 slots per XCD (256 = 8*32)
  const int cc = slot & 3, rloc = slot >> 2;       // 4 col-tiles, 8 row-bands
  const int m0 = (xcd * 8 + rloc) * 128, n0 = cc * 192;
  const int tid = threadIdx.x;
  const int wave = tid >> 6, lane = tid & 63;
  const int wm2 = (wave >> 2) * 64, wn2 = (wave & 3) * 48;
  const int lrow = lane & 15, quad = lane >> 4;
  const int key = lrow & 7;           // 128B rows: key=row&7

  f32x4 acc[4][3];
#pragma unroll
  for (int mi = 0; mi < 4; mi++)
#pragma unroll
    for (int ni = 0; ni < 3; ni++) acc[mi][ni] = (f32x4){0.f, 0.f, 0.f, 0.f};

  auto stageT = [&](int t) {
    if (t >= NTILES) return;
    const int k0 = t * 64;
    ushort_t* bufA = smem + (t % 3) * BUFU;
    ushort_t* bufB = bufA + 8192;
#pragma unroll
    for (int j = 0; j < 2; ++j) {        // A: 128 rows x 8 chunks = 1024
      int q = j * 512 + tid;
      int row = q >> 3;
      int sc = (q & 7) ^ (row & 7);
      async_cp16(A + (size_t)(m0 + row) * KD + k0 + sc * 8, bufA + q * 8);
    }
#pragma unroll
    for (int j = 0; j < 3; ++j) {        // B: 192 rows x 8 chunks = 1536
      int q = j * 512 + tid;
      int row = q >> 3;
      int sc = (q & 7) ^ (row & 7);
      async_cp16(Bw + (size_t)(n0 + row) * KD + k0 + sc * 8, bufB + q * 8);
    }
  };

  stageT(0); stageT(1);
  asm volatile("s_waitcnt vmcnt(5)" ::: "memory");
  __builtin_amdgcn_s_barrier();
  __builtin_amdgcn_sched_barrier(0);

  short8 af[4], bf[3];
  for (int t = 0; t < NTILES; ++t) {
    const ushort_t* Ab = smem + (t % 3) * BUFU;
    const ushort_t* Bb = Ab + 8192;

#pragma unroll
    for (int mi = 0; mi < 4; ++mi)
      af[mi] = *(const short8*)(Ab + (wm2 + mi * 16 + lrow) * 64 + ((quad ^ key) * 8));
#pragma unroll
    for (int ni = 0; ni < 3; ++ni)
      bf[ni] = *(const short8*)(Bb + (wn2 + ni * 16 + lrow) * 64 + ((quad ^ key) * 8));
    stageT(t + 2);
    asm volatile("s_waitcnt lgkmcnt(0)" ::: "memory");
    __builtin_amdgcn_sched_barrier(0);
    __builtin_amdgcn_s_setprio(1);
#pragma unroll
    for (int mi = 0; mi < 4; ++mi)
#pragma unroll
      for (int ni = 0; ni < 3; ++ni)
        acc[mi][ni] = __builtin_amdgcn_mfma_f32_16x16x32_bf16(af[mi], bf[ni], acc[mi][ni], 0, 0, 0);
    __builtin_amdgcn_s_setprio(0);
#pragma unroll
    for (int mi = 0; mi < 4; ++mi)
      af[mi] = *(const short8*)(Ab + (wm2 + mi * 16 + lrow) * 64 + (((4 + quad) ^ key) * 8));
#pragma unroll
    for (int ni = 0; ni < 3; ++ni)
      bf[ni] = *(const short8*)(Bb + (wn2 + ni * 16 + lrow) * 64 + (((4 + quad) ^ key) * 8));
    asm volatile("s_waitcnt lgkmcnt(0)" ::: "memory");
    __builtin_amdgcn_sched_barrier(0);
    __builtin_amdgcn_s_setprio(1);
#pragma unroll
    for (int mi = 0; mi < 4; ++mi)
#pragma unroll
      for (int ni = 0; ni < 3; ++ni)
        acc[mi][ni] = __builtin_amdgcn_mfma_f32_16x16x32_bf16(af[mi], bf[ni], acc[mi][ni], 0, 0, 0);
    __builtin_amdgcn_s_setprio(0);
    if (t < NTILES - 2) {
      asm volatile("s_waitcnt vmcnt(5)" ::: "memory");
    } else {
      asm volatile("s_waitcnt vmcnt(0)" ::: "memory");
    }
    __builtin_amdgcn_s_barrier();
    __builtin_amdgcn_sched_barrier(0);
  }

  // fused epilogue: + bias + residual -> fp32 (16-lane x 4B = 64B segments)
#pragma unroll
  for (int ni = 0; ni < 3; ++ni) {
    int col = n0 + wn2 + ni * 16 + lrow;
    float bc = bias[col];
#pragma unroll
    for (int mi = 0; mi < 4; ++mi) {
#pragma unroll
      for (int r = 0; r < 4; ++r) {
        int row = m0 + wm2 + mi * 16 + quad * 4 + r;
        size_t idx = (size_t)row * N + col;
        out[idx] = acc[mi][ni][r] + bc + res[idx];
      }
    }
  }
}

// ---------------- launch --------------------------------------------------------
extern "C" void kernel_launch(void* const* d_in, const int* in_sizes, int n_in,
                              void* d_out, int out_size, void* d_ws, size_t ws_size,
                              hipStream_t stream) {
  (void)in_sizes; (void)n_in; (void)out_size; (void)ws_size;
  const float* x   = (const float*)d_in[0];
  const float* g1  = (const float*)d_in[1];
  const float* be1 = (const float*)d_in[2];
  const float* Wq  = (const float*)d_in[3];
  const float* bq  = (const float*)d_in[4];
  const float* Wk  = (const float*)d_in[5];
  const float* bk  = (const float*)d_in[6];
  const float* Wv  = (const float*)d_in[7];
  const float* bv  = (const float*)d_in[8];
  const float* g2  = (const float*)d_in[9];
  const float* be2 = (const float*)d_in[10];
  const float* W1  = (const float*)d_in[11];
  const float* bm1 = (const float*)d_in[12];
  const float* W2  = (const float*)d_in[13];
  const float* bm2 = (const float*)d_in[14];
  float* outp = (float*)d_out;

  char* ws = (char*)d_ws;
  float*    out1 = (float*)ws;                   // [0, 25165824)
  ushort_t* hb   = (ushort_t*)(ws + 25165824);   // pre-attn bf16
  ushort_t* h2   = (ushort_t*)(ws + 25165824);   // post-attn bf16 (overlays hb)
  ushort_t* mb   = (ushort_t*)(ws + 37748736);
  ushort_t* Wc   = (ushort_t*)(ws + 88080384);
  ushort_t* W1b  = (ushort_t*)(ws + 88375296);
  ushort_t* W2b  = (ushort_t*)(ws + 93093888);
  float*    bcb  = (float*)(ws + 97812480);

  k_prep<<<dim3(5184 + NT / 4), dim3(256), 0, stream>>>(Wq, Wk, Wv, bq, bk, bv, W1, W2,
                                                        x, g1, be1, Wc, bcb, W1b, W2b, hb);
  k_fused<<<dim3(Bn * Hn), dim3(256), 0, stream>>>(hb, Wc, bcb, x, out1);
  k_ln2<<<dim3(NT / 4), dim3(256), 0, stream>>>(out1, g2, be2, h2);
  k_gemm1<<<dim3(512), dim3(512), 0, stream>>>(h2, W1b, bm1, mb);
  k_gemm2<<<dim3(256), dim3(512), 0, stream>>>(mb, W2b, bm2, out1, outp);
}